// Round 1
// baseline (2803.048 us; speedup 1.0000x reference)
//
#include <hip/hip_runtime.h>
#include <math.h>

// Problem constants (fixed-shape problem: B=8, T=2048, C=1024, fp32)
#define B_DIM 8
#define T_DIM 2048
#define C_DIM 1024
#define BT_DIM (B_DIM * T_DIM)                 // 16384 rows
#define FSZ ((size_t)BT_DIM * C_DIM)           // 16,777,216 floats per [B,T,C] tensor
#define LN_EPS 1e-5f

// ---------------------------------------------------------------------------
// GEMM: Y[M,N] = X[M,K] @ W[K,N] + bias[N], optional ReLU.  fp32, 64x64x16
// tiles, 256 threads, 4x4 per-thread micro-tile. Correctness-first baseline.
// ---------------------------------------------------------------------------
__global__ __launch_bounds__(256)
void gemm_bias_kernel(const float* __restrict__ X, const float* __restrict__ W,
                      const float* __restrict__ bias, float* __restrict__ Y,
                      int M, int N, int K, int do_relu) {
  __shared__ float Xs[16][68];   // [k][m], padded row (68*4B = 17*16B, float4-aligned)
  __shared__ float Ws[16][64];   // [k][n]
  const int tid = threadIdx.x;
  const int tx = tid & 15, ty = tid >> 4;
  const int m0 = blockIdx.y * 64, n0 = blockIdx.x * 64;

  const int li = tid >> 2;         // m index for X load (0..63)
  const int lj = (tid & 3) << 2;   // k offset for X load
  const int wj = tid >> 4;         // k index for W load (0..15)
  const int wn = (tid & 15) << 2;  // n offset for W load

  float acc[4][4] = {{0.f}};

  for (int k0 = 0; k0 < K; k0 += 16) {
    float4 xv = *(const float4*)(X + (size_t)(m0 + li) * K + k0 + lj);
    Xs[lj + 0][li] = xv.x;
    Xs[lj + 1][li] = xv.y;
    Xs[lj + 2][li] = xv.z;
    Xs[lj + 3][li] = xv.w;
    *(float4*)&Ws[wj][wn] = *(const float4*)(W + (size_t)(k0 + wj) * N + n0 + wn);
    __syncthreads();
#pragma unroll
    for (int kk = 0; kk < 16; kk++) {
      float4 a = *(const float4*)&Xs[kk][ty << 2];
      float4 b = *(const float4*)&Ws[kk][tx << 2];
      float av[4] = {a.x, a.y, a.z, a.w};
      float bv[4] = {b.x, b.y, b.z, b.w};
#pragma unroll
      for (int u = 0; u < 4; u++)
#pragma unroll
        for (int v = 0; v < 4; v++) acc[u][v] = fmaf(av[u], bv[v], acc[u][v]);
    }
    __syncthreads();
  }

  float4 bb = *(const float4*)(bias + n0 + (tx << 2));
#pragma unroll
  for (int u = 0; u < 4; u++) {
    float4 o = make_float4(acc[u][0] + bb.x, acc[u][1] + bb.y,
                           acc[u][2] + bb.z, acc[u][3] + bb.w);
    if (do_relu) {
      o.x = fmaxf(o.x, 0.f); o.y = fmaxf(o.y, 0.f);
      o.z = fmaxf(o.z, 0.f); o.w = fmaxf(o.w, 0.f);
    }
    *(float4*)(Y + (size_t)(m0 + (ty << 2) + u) * N + n0 + (tx << 2)) = o;
  }
}

// ---------------------------------------------------------------------------
// Row sum over channels: sv[r] = sum_c v[r, c]   (r in [0, B*T))
// ---------------------------------------------------------------------------
__global__ __launch_bounds__(256)
void rowsum_kernel(const float* __restrict__ v, float* __restrict__ sv) {
  const int r = blockIdx.x;
  const int tid = threadIdx.x;
  float4 t4 = *(const float4*)(v + (size_t)r * C_DIM + (tid << 2));
  float s = t4.x + t4.y + t4.z + t4.w;
#pragma unroll
  for (int off = 32; off > 0; off >>= 1) s += __shfl_down(s, off);
  __shared__ float ps[4];
  if ((tid & 63) == 0) ps[tid >> 6] = s;
  __syncthreads();
  if (tid == 0) sv[r] = ps[0] + ps[1] + ps[2] + ps[3];
}

// ---------------------------------------------------------------------------
// 2048-point complex Stockham FFT in LDS (radix-2, 11 stages, autosorting).
// sign = -1: forward DFT; sign = +1: unnormalized inverse.
// Returns pointer to the buffer holding the result. Caller must __syncthreads()
// before calling (input visible); function syncs after every stage.
// ---------------------------------------------------------------------------
__device__ float2* fft2048(float2* a, float2* b, int tid, float sign) {
  float2* src = a;
  float2* dst = b;
#pragma unroll 1
  for (int s = 0; s < 11; s++) {
    const int m = 1 << s;
#pragma unroll 1
    for (int i = tid; i < 1024; i += 256) {
      const int kk = i & (m - 1);
      float2 c0 = src[i];
      float2 c1 = src[i + 1024];
      float ang = sign * (6.283185307179586f / 2048.0f) * (float)(i - kk);
      float sw, cw;
      __sincosf(ang, &sw, &cw);
      float dx = c0.x - c1.x, dy = c0.y - c1.y;
      const int o0 = (i << 1) - kk;   // kk + 2*(i-kk)*... = 2i - kk
      dst[o0] = make_float2(c0.x + c1.x, c0.y + c1.y);
      dst[o0 + m] = make_float2(cw * dx - sw * dy, cw * dy + sw * dx);
    }
    __syncthreads();
    float2* t = src; src = dst; dst = t;
  }
  return src;  // after final swap, src == last-written buffer
}

// ---------------------------------------------------------------------------
// Circular cross-correlation along T for one (batch, channel-pair) per block:
//   corr[b,:,c] = irfft(rfft(q[b,:,c]) * conj(rfft(k[b,:,c])))
// Two real channels packed into one complex signal; Hermitian unpack in the
// pointwise stage. Writes corr in place over q (disjoint columns per block).
// ---------------------------------------------------------------------------
__global__ __launch_bounds__(256)
void corr_fft_kernel(const float* q, const float* k, float* corr) {
  __shared__ float2 bA[2048];
  __shared__ float2 bB[2048];
  __shared__ float2 bC[2048];
  const int tid = threadIdx.x;
  const int b = blockIdx.y;
  const int c0 = blockIdx.x * 2;
  const float* qb = q + (size_t)b * T_DIM * C_DIM;
  const float* kb = k + (size_t)b * T_DIM * C_DIM;

  // load packed zq = q_c0 + i*q_{c0+1}
#pragma unroll 1
  for (int t = tid; t < T_DIM; t += 256)
    bA[t] = *(const float2*)(qb + (size_t)t * C_DIM + c0);
  __syncthreads();
  float2* FQ = fft2048(bA, bB, tid, -1.0f);   // -> bB

  // load packed zk
#pragma unroll 1
  for (int t = tid; t < T_DIM; t += 256)
    bA[t] = *(const float2*)(kb + (size_t)t * C_DIM + c0);
  __syncthreads();
  float2* FK = fft2048(bA, bC, tid, -1.0f);   // -> bC (bB untouched)

  // pointwise: unpack A/B spectra, cross-spectra G,H, repack W = G + i*H -> bA
#pragma unroll 1
  for (int f = tid; f < T_DIM; f += 256) {
    const int f2 = (T_DIM - f) & (T_DIM - 1);
    float2 Zq = FQ[f], Zq2 = FQ[f2];
    float2 Zk = FK[f], Zk2 = FK[f2];
    // Aq = (Zq + conj(Zq2))/2 ; Bq = (Zq - conj(Zq2))/(2i)
    float2 Aq = make_float2(0.5f * (Zq.x + Zq2.x), 0.5f * (Zq.y - Zq2.y));
    float2 Dq = make_float2(Zq.x - Zq2.x, Zq.y + Zq2.y);
    float2 Bq = make_float2(0.5f * Dq.y, -0.5f * Dq.x);
    float2 Ak = make_float2(0.5f * (Zk.x + Zk2.x), 0.5f * (Zk.y - Zk2.y));
    float2 Dk = make_float2(Zk.x - Zk2.x, Zk.y + Zk2.y);
    float2 Bk = make_float2(0.5f * Dk.y, -0.5f * Dk.x);
    // G = Aq * conj(Ak); H = Bq * conj(Bk)
    float2 G = make_float2(Aq.x * Ak.x + Aq.y * Ak.y, Aq.y * Ak.x - Aq.x * Ak.y);
    float2 H = make_float2(Bq.x * Bk.x + Bq.y * Bk.y, Bq.y * Bk.x - Bq.x * Bk.y);
    bA[f] = make_float2(G.x - H.y, G.y + H.x);  // W = G + i*H
  }
  __syncthreads();
  float2* OUT = fft2048(bA, bB, tid, +1.0f);    // inverse (unnormalized) -> bB

  float* cb = corr + (size_t)b * T_DIM * C_DIM;
  const float sc = 1.0f / 2048.0f;
#pragma unroll 1
  for (int t = tid; t < T_DIM; t += 256) {
    float2 o = OUT[t];
    *(float2*)(cb + (size_t)t * C_DIM + c0) = make_float2(o.x * sc, o.y * sc);
  }
}

// ---------------------------------------------------------------------------
// Softmax over T (axis=1) per (b,c), fused with attn = weights * sv[b,t].
// In-place on corr. Block: (c-block of 32, b). 256 threads = 32 c-lanes x 8 t-lanes.
// ---------------------------------------------------------------------------
__global__ __launch_bounds__(256)
void softmax_attn_kernel(float* corr, const float* __restrict__ sv) {
  const int tid = threadIdx.x;
  const int cc = tid & 31;         // channel lane
  const int tt = tid >> 5;         // 0..7
  const int b = blockIdx.y;
  const int c = blockIdx.x * 32 + cc;
  float* cb = corr + (size_t)b * T_DIM * C_DIM;
  const float* svb = sv + (size_t)b * T_DIM;

  float m = -INFINITY, s = 0.f;
#pragma unroll 1
  for (int t = tt; t < T_DIM; t += 8) {
    float v = cb[(size_t)t * C_DIM + c];
    float nm = fmaxf(m, v);
    s = s * __expf(m - nm) + __expf(v - nm);
    m = nm;
  }
  __shared__ float ms[8][32];
  __shared__ float ss[8][32];
  ms[tt][cc] = m;
  ss[tt][cc] = s;
  __syncthreads();
  float M = -INFINITY;
#pragma unroll
  for (int i = 0; i < 8; i++) M = fmaxf(M, ms[i][cc]);
  float S = 0.f;
#pragma unroll
  for (int i = 0; i < 8; i++) S += ss[i][cc] * __expf(ms[i][cc] - M);
  const float inv = 1.0f / S;
#pragma unroll 1
  for (int t = tt; t < T_DIM; t += 8) {
    size_t idx = (size_t)t * C_DIM + c;
    float v = cb[idx];
    cb[idx] = __expf(v - M) * inv * svb[t];
  }
}

// ---------------------------------------------------------------------------
// out[r,:] = LayerNorm(a[r,:] + b[r,:]) * g + be      (one block per row)
// ---------------------------------------------------------------------------
__global__ __launch_bounds__(256)
void add_ln_kernel(const float* __restrict__ A, const float* __restrict__ Bv,
                   const float* __restrict__ g, const float* __restrict__ be,
                   float* __restrict__ out) {
  const int r = blockIdx.x;
  const int tid = threadIdx.x;
  const size_t base = (size_t)r * C_DIM + (tid << 2);
  float4 a = *(const float4*)(A + base);
  float4 b = *(const float4*)(Bv + base);
  float x0 = a.x + b.x, x1 = a.y + b.y, x2 = a.z + b.z, x3 = a.w + b.w;
  float s = x0 + x1 + x2 + x3;
  float s2 = x0 * x0 + x1 * x1 + x2 * x2 + x3 * x3;
#pragma unroll
  for (int off = 32; off > 0; off >>= 1) {
    s += __shfl_down(s, off);
    s2 += __shfl_down(s2, off);
  }
  __shared__ float ps[4], ps2[4];
  if ((tid & 63) == 0) { ps[tid >> 6] = s; ps2[tid >> 6] = s2; }
  __syncthreads();
  float S = ps[0] + ps[1] + ps[2] + ps[3];
  float S2 = ps2[0] + ps2[1] + ps2[2] + ps2[3];
  const float mu = S * (1.0f / C_DIM);
  const float var = S2 * (1.0f / C_DIM) - mu * mu;
  const float rs = rsqrtf(var + LN_EPS);
  float4 gv = *(const float4*)(g + (tid << 2));
  float4 bev = *(const float4*)(be + (tid << 2));
  float4 o = make_float4((x0 - mu) * rs * gv.x + bev.x,
                         (x1 - mu) * rs * gv.y + bev.y,
                         (x2 - mu) * rs * gv.z + bev.z,
                         (x3 - mu) * rs * gv.w + bev.w);
  *(float4*)(out + base) = o;
}

// ---------------------------------------------------------------------------
extern "C" void kernel_launch(void* const* d_in, const int* in_sizes, int n_in,
                              void* d_out, int out_size, void* d_ws, size_t ws_size,
                              hipStream_t stream) {
  const float* x   = (const float*)d_in[0];
  const float* Wq  = (const float*)d_in[1];
  const float* bq  = (const float*)d_in[2];
  const float* Wk  = (const float*)d_in[3];
  const float* bk  = (const float*)d_in[4];
  const float* Wv  = (const float*)d_in[5];
  const float* bv  = (const float*)d_in[6];
  const float* g1  = (const float*)d_in[7];
  const float* be1 = (const float*)d_in[8];
  const float* W1  = (const float*)d_in[9];
  const float* bf1 = (const float*)d_in[10];
  const float* W2  = (const float*)d_in[11];
  const float* bf2 = (const float*)d_in[12];
  const float* g2  = (const float*)d_in[13];
  const float* be2 = (const float*)d_in[14];
  float* out = (float*)d_out;

  // Workspace layout (floats): 3 big buffers + sv, with in-place reuse.
  float* ws   = (float*)d_ws;
  float* qbuf = ws;               // q -> corr -> attn (in place) -> later h2
  float* kbuf = ws + FSZ;         // k -> x1
  float* vbuf = ws + 2 * FSZ;     // v -> h1
  float* sv   = ws + 3 * FSZ;     // [B*T]

  const dim3 gemm_grid(C_DIM / 64, BT_DIM / 64);  // (16, 256)
  const dim3 blk(256);

  // q, k, v projections
  gemm_bias_kernel<<<gemm_grid, blk, 0, stream>>>(x, Wq, bq, qbuf, BT_DIM, C_DIM, C_DIM, 0);
  gemm_bias_kernel<<<gemm_grid, blk, 0, stream>>>(x, Wk, bk, kbuf, BT_DIM, C_DIM, C_DIM, 0);
  gemm_bias_kernel<<<gemm_grid, blk, 0, stream>>>(x, Wv, bv, vbuf, BT_DIM, C_DIM, C_DIM, 0);

  // sv[b,t] = sum_c v
  rowsum_kernel<<<dim3(BT_DIM), blk, 0, stream>>>(vbuf, sv);

  // corr via FFT (in place over q; k consumed)
  corr_fft_kernel<<<dim3(C_DIM / 2, B_DIM), blk, 0, stream>>>(qbuf, kbuf, qbuf);

  // softmax over T fused with * sv  (in place -> attn)
  softmax_attn_kernel<<<dim3(C_DIM / 32, B_DIM), blk, 0, stream>>>(qbuf, sv);

  // x1 = LN(x + attn) -> kbuf
  add_ln_kernel<<<dim3(BT_DIM), blk, 0, stream>>>(x, qbuf, g1, be1, kbuf);

  // h1 = relu(x1 @ W1 + bf1) -> vbuf
  gemm_bias_kernel<<<gemm_grid, blk, 0, stream>>>(kbuf, W1, bf1, vbuf, BT_DIM, C_DIM, C_DIM, 1);

  // h2 = h1 @ W2 + bf2 -> qbuf
  gemm_bias_kernel<<<gemm_grid, blk, 0, stream>>>(vbuf, W2, bf2, qbuf, BT_DIM, C_DIM, C_DIM, 0);

  // out = LN(x1 + h2)
  add_ln_kernel<<<dim3(BT_DIM), blk, 0, stream>>>(kbuf, qbuf, g2, be2, out);
}

// Round 2
// 1010.706 us; speedup vs baseline: 2.7734x; 2.7734x over previous
//
#include <hip/hip_runtime.h>
#include <math.h>

// Problem constants (fixed-shape: B=8, T=2048, C=1024, fp32 in/out)
#define B_DIM 8
#define T_DIM 2048
#define C_DIM 1024
#define BT_DIM (B_DIM * T_DIM)                 // 16384 rows
#define FSZ ((size_t)BT_DIM * C_DIM)           // 16,777,216 elements per [B,T,C]
#define LN_EPS 1e-5f

typedef __bf16 bf16x8 __attribute__((ext_vector_type(8)));
typedef float f32x4 __attribute__((ext_vector_type(4)));

__device__ __forceinline__ unsigned short f2bf(float f) {
  __bf16 h = (__bf16)f;
  return __builtin_bit_cast(unsigned short, h);
}

// async global->LDS, 16 B per lane. LDS dest must be wave-uniform base + lane*16.
__device__ __forceinline__ void gld16(const void* g, void* l) {
  __builtin_amdgcn_global_load_lds(
      (const __attribute__((address_space(1))) unsigned int*)g,
      (__attribute__((address_space(3))) unsigned int*)l, 16, 0, 0);
}

// ---------------------------------------------------------------------------
// x fp32 -> (hi, lo) bf16 split: hi = bf16(x), lo = bf16(x - hi)
// ---------------------------------------------------------------------------
__global__ __launch_bounds__(256)
void cvt_split_kernel(const float* __restrict__ x, unsigned short* __restrict__ hi,
                      unsigned short* __restrict__ lo) {
  size_t idx = ((size_t)blockIdx.x * 256 + threadIdx.x) * 4;
  float4 v = *(const float4*)(x + idx);
  float f[4] = {v.x, v.y, v.z, v.w};
  ushort4 h, l;
  unsigned short hv[4], lv[4];
#pragma unroll
  for (int i = 0; i < 4; i++) {
    __bf16 hb = (__bf16)f[i];
    hv[i] = __builtin_bit_cast(unsigned short, hb);
    lv[i] = f2bf(f[i] - (float)hb);
  }
  h = make_ushort4(hv[0], hv[1], hv[2], hv[3]);
  l = make_ushort4(lv[0], lv[1], lv[2], lv[3]);
  *(ushort4*)(hi + idx) = h;
  *(ushort4*)(lo + idx) = l;
}

// ---------------------------------------------------------------------------
// W [K,N] fp32 -> Wt [N,K] bf16 (hi only, or hi+lo split). 32x32 LDS tiles.
// ---------------------------------------------------------------------------
__global__ __launch_bounds__(256)
void wtrans_kernel(const float* __restrict__ W, unsigned short* __restrict__ Wt_hi,
                   unsigned short* __restrict__ Wt_lo, int K, int N) {
  __shared__ float tile[32][33];
  const int tid = threadIdx.x;
  const int tx = tid & 31, ty = tid >> 5;  // ty 0..7
  const int n0 = blockIdx.x * 32, k0 = blockIdx.y * 32;
#pragma unroll
  for (int i = 0; i < 4; i++) {
    int row = ty + i * 8;
    tile[row][tx] = W[(size_t)(k0 + row) * N + n0 + tx];
  }
  __syncthreads();
#pragma unroll
  for (int i = 0; i < 4; i++) {
    int row = ty + i * 8;                  // output n-row
    float v = tile[tx][row];               // W[k0+tx][n0+row]
    __bf16 hb = (__bf16)v;
    Wt_hi[(size_t)(n0 + row) * K + k0 + tx] = __builtin_bit_cast(unsigned short, hb);
    if (Wt_lo) Wt_lo[(size_t)(n0 + row) * K + k0 + tx] = f2bf(v - (float)hb);
  }
}

// ---------------------------------------------------------------------------
// wvsum[k] = sum_n Wv[k,n]  (blocks 0..K-1); block K reduces bv -> bvsum.
// ---------------------------------------------------------------------------
__global__ __launch_bounds__(256)
void wv_rowsum_kernel(const float* __restrict__ Wv, const float* __restrict__ bv,
                      float* __restrict__ wvsum, float* __restrict__ bvsum) {
  const int r = blockIdx.x;
  const int tid = threadIdx.x;
  const float* src = (r < C_DIM) ? (Wv + (size_t)r * C_DIM) : bv;
  float4 t4 = *(const float4*)(src + (tid << 2));
  float s = t4.x + t4.y + t4.z + t4.w;
#pragma unroll
  for (int off = 32; off > 0; off >>= 1) s += __shfl_down(s, off);
  __shared__ float ps[4];
  if ((tid & 63) == 0) ps[tid >> 6] = s;
  __syncthreads();
  if (tid == 0) {
    float v = ps[0] + ps[1] + ps[2] + ps[3];
    if (r < C_DIM) wvsum[r] = v; else bvsum[0] = v;
  }
}

// ---------------------------------------------------------------------------
// sv[r] = dot(x[r,:], wvsum) + bvsum   (replaces the whole v GEMM + rowsum)
// ---------------------------------------------------------------------------
__global__ __launch_bounds__(256)
void sv_dot_kernel(const float* __restrict__ x, const float* __restrict__ wvsum,
                   const float* __restrict__ bvsum, float* __restrict__ sv) {
  const int r = blockIdx.x;
  const int tid = threadIdx.x;
  float4 a = *(const float4*)(x + (size_t)r * C_DIM + (tid << 2));
  float4 w = *(const float4*)(wvsum + (tid << 2));
  float s = a.x * w.x + a.y * w.y + a.z * w.z + a.w * w.w;
#pragma unroll
  for (int off = 32; off > 0; off >>= 1) s += __shfl_down(s, off);
  __shared__ float ps[4];
  if ((tid & 63) == 0) ps[tid >> 6] = s;
  __syncthreads();
  if (tid == 0) sv[r] = ps[0] + ps[1] + ps[2] + ps[3] + bvsum[0];
}

// ---------------------------------------------------------------------------
// bf16 MFMA GEMM (m97 structure): Y[M,N] = A[M,K] @ Bt[N,K]^T + bias.
// 128x128 tile, BK=32, 256 thr = 4 waves in 2x2, 4x4 MFMA tiles/wave.
// XOR-swizzled LDS k-slots -> fragment ds_read_b128 at worst 2-way conflicts.
// Yf (fp32) and Yb (bf16) outputs each optional.
// ---------------------------------------------------------------------------
__global__ __launch_bounds__(256, 2)
void gemm_bf16_kernel(const __bf16* __restrict__ A, const __bf16* __restrict__ Bt,
                      const float* __restrict__ bias, float* Yf, unsigned short* Yb,
                      int K, int N, int do_relu) {
  __shared__ __align__(16) __bf16 As[128 * 32];
  __shared__ __align__(16) __bf16 Bs[128 * 32];
  const int tid = threadIdx.x;
  const int wave = tid >> 6, lane = tid & 63;
  const int wr = wave >> 1, wc = wave & 1;
  const int r15 = lane & 15, kq = lane >> 4;
  const int m0 = blockIdx.y * 128, n0 = blockIdx.x * 128;

  f32x4 acc[4][4] = {};

  for (int k0 = 0; k0 < K; k0 += 32) {
#pragma unroll
    for (int r = 0; r < 2; ++r) {
      int idx = r * 256 + tid;
      int row = idx >> 2;
      int ko = (idx & 3) ^ ((row >> 1) & 3);
      gld16(A + (size_t)(m0 + row) * K + k0 + ko * 8, &As[idx * 8]);
      gld16(Bt + (size_t)(n0 + row) * K + k0 + ko * 8, &Bs[idx * 8]);
    }
    __syncthreads();
    bf16x8 afr[4], bfr[4];
#pragma unroll
    for (int i = 0; i < 4; i++) {
      int ar = wr * 64 + i * 16 + r15;
      afr[i] = *(const bf16x8*)&As[(ar * 4 + (kq ^ ((ar >> 1) & 3))) * 8];
      int br = wc * 64 + i * 16 + r15;
      bfr[i] = *(const bf16x8*)&Bs[(br * 4 + (kq ^ ((br >> 1) & 3))) * 8];
    }
#pragma unroll
    for (int mi = 0; mi < 4; mi++)
#pragma unroll
      for (int ni = 0; ni < 4; ni++)
        acc[mi][ni] = __builtin_amdgcn_mfma_f32_16x16x32_bf16(afr[mi], bfr[ni], acc[mi][ni], 0, 0, 0);
    __syncthreads();
  }

  float bv[4];
#pragma unroll
  for (int ni = 0; ni < 4; ni++) bv[ni] = bias[n0 + wc * 64 + ni * 16 + r15];

#pragma unroll
  for (int mi = 0; mi < 4; mi++)
#pragma unroll
    for (int ni = 0; ni < 4; ni++) {
      const int n = n0 + wc * 64 + ni * 16 + r15;
#pragma unroll
      for (int r = 0; r < 4; r++) {
        const int m = m0 + wr * 64 + mi * 16 + kq * 4 + r;
        float v = acc[mi][ni][r] + bv[ni];
        if (do_relu) v = fmaxf(v, 0.f);
        if (Yf) Yf[(size_t)m * N + n] = v;
        if (Yb) Yb[(size_t)m * N + n] = f2bf(v);
      }
    }
}

// ---------------------------------------------------------------------------
// Split-precision GEMM: Y = (Ahi+Alo) @ (Bhi+Blo)^T + bias, fp32 out.
// 3 MFMA passes per tile: hi*hi + hi*lo + lo*hi (lo*lo dropped, ~2^-18 rel).
// ---------------------------------------------------------------------------
__global__ __launch_bounds__(256, 2)
void gemm_split_kernel(const __bf16* __restrict__ Ahi, const __bf16* __restrict__ Alo,
                       const __bf16* __restrict__ Bhi, const __bf16* __restrict__ Blo,
                       const float* __restrict__ bias, float* __restrict__ Yf,
                       int K, int N) {
  __shared__ __align__(16) __bf16 Ash[128 * 32];
  __shared__ __align__(16) __bf16 Asl[128 * 32];
  __shared__ __align__(16) __bf16 Bsh[128 * 32];
  __shared__ __align__(16) __bf16 Bsl[128 * 32];
  const int tid = threadIdx.x;
  const int wave = tid >> 6, lane = tid & 63;
  const int wr = wave >> 1, wc = wave & 1;
  const int r15 = lane & 15, kq = lane >> 4;
  const int m0 = blockIdx.y * 128, n0 = blockIdx.x * 128;

  f32x4 acc[4][4] = {};

  for (int k0 = 0; k0 < K; k0 += 32) {
#pragma unroll
    for (int r = 0; r < 2; ++r) {
      int idx = r * 256 + tid;
      int row = idx >> 2;
      int ko = (idx & 3) ^ ((row >> 1) & 3);
      size_t ga = (size_t)(m0 + row) * K + k0 + ko * 8;
      size_t gb = (size_t)(n0 + row) * K + k0 + ko * 8;
      gld16(Ahi + ga, &Ash[idx * 8]);
      gld16(Alo + ga, &Asl[idx * 8]);
      gld16(Bhi + gb, &Bsh[idx * 8]);
      gld16(Blo + gb, &Bsl[idx * 8]);
    }
    __syncthreads();
    bf16x8 ah[4], al[4], bh[4], bl[4];
#pragma unroll
    for (int i = 0; i < 4; i++) {
      int ar = wr * 64 + i * 16 + r15;
      int as = (ar * 4 + (kq ^ ((ar >> 1) & 3))) * 8;
      ah[i] = *(const bf16x8*)&Ash[as];
      al[i] = *(const bf16x8*)&Asl[as];
      int br = wc * 64 + i * 16 + r15;
      int bs = (br * 4 + (kq ^ ((br >> 1) & 3))) * 8;
      bh[i] = *(const bf16x8*)&Bsh[bs];
      bl[i] = *(const bf16x8*)&Bsl[bs];
    }
#pragma unroll
    for (int mi = 0; mi < 4; mi++)
#pragma unroll
      for (int ni = 0; ni < 4; ni++) {
        f32x4 c = acc[mi][ni];
        c = __builtin_amdgcn_mfma_f32_16x16x32_bf16(ah[mi], bh[ni], c, 0, 0, 0);
        c = __builtin_amdgcn_mfma_f32_16x16x32_bf16(ah[mi], bl[ni], c, 0, 0, 0);
        c = __builtin_amdgcn_mfma_f32_16x16x32_bf16(al[mi], bh[ni], c, 0, 0, 0);
        acc[mi][ni] = c;
      }
    __syncthreads();
  }

  float bv[4];
#pragma unroll
  for (int ni = 0; ni < 4; ni++) bv[ni] = bias[n0 + wc * 64 + ni * 16 + r15];

#pragma unroll
  for (int mi = 0; mi < 4; mi++)
#pragma unroll
    for (int ni = 0; ni < 4; ni++) {
      const int n = n0 + wc * 64 + ni * 16 + r15;
#pragma unroll
      for (int r = 0; r < 4; r++) {
        const int m = m0 + wr * 64 + mi * 16 + kq * 4 + r;
        Yf[(size_t)m * N + n] = acc[mi][ni][r] + bv[ni];
      }
    }
}

// ---------------------------------------------------------------------------
// 2048-point complex Stockham FFT in LDS (radix-2, 11 stages).
// ---------------------------------------------------------------------------
__device__ float2* fft2048(float2* a, float2* b, int tid, float sign) {
  float2* src = a;
  float2* dst = b;
#pragma unroll 1
  for (int s = 0; s < 11; s++) {
    const int m = 1 << s;
#pragma unroll 1
    for (int i = tid; i < 1024; i += 256) {
      const int kk = i & (m - 1);
      float2 c0 = src[i];
      float2 c1 = src[i + 1024];
      float ang = sign * (6.283185307179586f / 2048.0f) * (float)(i - kk);
      float sw, cw;
      __sincosf(ang, &sw, &cw);
      float dx = c0.x - c1.x, dy = c0.y - c1.y;
      const int o0 = (i << 1) - kk;
      dst[o0] = make_float2(c0.x + c1.x, c0.y + c1.y);
      dst[o0 + m] = make_float2(cw * dx - sw * dy, cw * dy + sw * dx);
    }
    __syncthreads();
    float2* t = src; src = dst; dst = t;
  }
  return src;
}

// corr[b,:,c] = irfft(rfft(q)*conj(rfft(k))) along T; 2 channels/block packed.
__global__ __launch_bounds__(256)
void corr_fft_kernel(const float* q, const float* k, float* corr) {
  __shared__ float2 bA[2048];
  __shared__ float2 bB[2048];
  __shared__ float2 bC[2048];
  const int tid = threadIdx.x;
  const int b = blockIdx.y;
  const int c0 = blockIdx.x * 2;
  const float* qb = q + (size_t)b * T_DIM * C_DIM;
  const float* kb = k + (size_t)b * T_DIM * C_DIM;

#pragma unroll 1
  for (int t = tid; t < T_DIM; t += 256)
    bA[t] = *(const float2*)(qb + (size_t)t * C_DIM + c0);
  __syncthreads();
  float2* FQ = fft2048(bA, bB, tid, -1.0f);

#pragma unroll 1
  for (int t = tid; t < T_DIM; t += 256)
    bA[t] = *(const float2*)(kb + (size_t)t * C_DIM + c0);
  __syncthreads();
  float2* FK = fft2048(bA, bC, tid, -1.0f);

#pragma unroll 1
  for (int f = tid; f < T_DIM; f += 256) {
    const int f2 = (T_DIM - f) & (T_DIM - 1);
    float2 Zq = FQ[f], Zq2 = FQ[f2];
    float2 Zk = FK[f], Zk2 = FK[f2];
    float2 Aq = make_float2(0.5f * (Zq.x + Zq2.x), 0.5f * (Zq.y - Zq2.y));
    float2 Dq = make_float2(Zq.x - Zq2.x, Zq.y + Zq2.y);
    float2 Bq = make_float2(0.5f * Dq.y, -0.5f * Dq.x);
    float2 Ak = make_float2(0.5f * (Zk.x + Zk2.x), 0.5f * (Zk.y - Zk2.y));
    float2 Dk = make_float2(Zk.x - Zk2.x, Zk.y + Zk2.y);
    float2 Bk = make_float2(0.5f * Dk.y, -0.5f * Dk.x);
    float2 G = make_float2(Aq.x * Ak.x + Aq.y * Ak.y, Aq.y * Ak.x - Aq.x * Ak.y);
    float2 H = make_float2(Bq.x * Bk.x + Bq.y * Bk.y, Bq.y * Bk.x - Bq.x * Bk.y);
    bA[f] = make_float2(G.x - H.y, G.y + H.x);
  }
  __syncthreads();
  float2* OUT = fft2048(bA, bB, tid, +1.0f);

  float* cb = corr + (size_t)b * T_DIM * C_DIM;
  const float sc = 1.0f / 2048.0f;
#pragma unroll 1
  for (int t = tid; t < T_DIM; t += 256) {
    float2 o = OUT[t];
    *(float2*)(cb + (size_t)t * C_DIM + c0) = make_float2(o.x * sc, o.y * sc);
  }
}

// ---------------------------------------------------------------------------
// Softmax over T per (b,c), fused with attn = weights * sv[b,t]. In place.
// ---------------------------------------------------------------------------
__global__ __launch_bounds__(256)
void softmax_attn_kernel(float* corr, const float* __restrict__ sv) {
  const int tid = threadIdx.x;
  const int cc = tid & 31;
  const int tt = tid >> 5;
  const int b = blockIdx.y;
  const int c = blockIdx.x * 32 + cc;
  float* cb = corr + (size_t)b * T_DIM * C_DIM;
  const float* svb = sv + (size_t)b * T_DIM;

  float m = -INFINITY, s = 0.f;
#pragma unroll 1
  for (int t = tt; t < T_DIM; t += 8) {
    float v = cb[(size_t)t * C_DIM + c];
    float nm = fmaxf(m, v);
    s = s * __expf(m - nm) + __expf(v - nm);
    m = nm;
  }
  __shared__ float ms[8][32];
  __shared__ float ss[8][32];
  ms[tt][cc] = m;
  ss[tt][cc] = s;
  __syncthreads();
  float M = -INFINITY;
#pragma unroll
  for (int i = 0; i < 8; i++) M = fmaxf(M, ms[i][cc]);
  float S = 0.f;
#pragma unroll
  for (int i = 0; i < 8; i++) S += ss[i][cc] * __expf(ms[i][cc] - M);
  const float inv = 1.0f / S;
#pragma unroll 1
  for (int t = tt; t < T_DIM; t += 8) {
    size_t idx = (size_t)t * C_DIM + c;
    float v = cb[idx];
    cb[idx] = __expf(v - M) * inv * svb[t];
  }
}

// ---------------------------------------------------------------------------
// out = LayerNorm(A + Bv) * g + be; optional bf16 copy of out.
// ---------------------------------------------------------------------------
__global__ __launch_bounds__(256)
void add_ln_kernel(const float* __restrict__ A, const float* __restrict__ Bv,
                   const float* __restrict__ g, const float* __restrict__ be,
                   float* __restrict__ outf, unsigned short* outb) {
  const int r = blockIdx.x;
  const int tid = threadIdx.x;
  const size_t base = (size_t)r * C_DIM + (tid << 2);
  float4 a = *(const float4*)(A + base);
  float4 b = *(const float4*)(Bv + base);
  float x0 = a.x + b.x, x1 = a.y + b.y, x2 = a.z + b.z, x3 = a.w + b.w;
  float s = x0 + x1 + x2 + x3;
  float s2 = x0 * x0 + x1 * x1 + x2 * x2 + x3 * x3;
#pragma unroll
  for (int off = 32; off > 0; off >>= 1) {
    s += __shfl_down(s, off);
    s2 += __shfl_down(s2, off);
  }
  __shared__ float ps[4], ps2[4];
  if ((tid & 63) == 0) { ps[tid >> 6] = s; ps2[tid >> 6] = s2; }
  __syncthreads();
  float S = ps[0] + ps[1] + ps[2] + ps[3];
  float S2 = ps2[0] + ps2[1] + ps2[2] + ps2[3];
  const float mu = S * (1.0f / C_DIM);
  const float var = S2 * (1.0f / C_DIM) - mu * mu;
  const float rs = rsqrtf(var + LN_EPS);
  float4 gv = *(const float4*)(g + (tid << 2));
  float4 bev = *(const float4*)(be + (tid << 2));
  float o0 = (x0 - mu) * rs * gv.x + bev.x;
  float o1 = (x1 - mu) * rs * gv.y + bev.y;
  float o2 = (x2 - mu) * rs * gv.z + bev.z;
  float o3 = (x3 - mu) * rs * gv.w + bev.w;
  *(float4*)(outf + base) = make_float4(o0, o1, o2, o3);
  if (outb) *(ushort4*)(outb + base) = make_ushort4(f2bf(o0), f2bf(o1), f2bf(o2), f2bf(o3));
}

// ---------------------------------------------------------------------------
extern "C" void kernel_launch(void* const* d_in, const int* in_sizes, int n_in,
                              void* d_out, int out_size, void* d_ws, size_t ws_size,
                              hipStream_t stream) {
  const float* x   = (const float*)d_in[0];
  const float* Wq  = (const float*)d_in[1];
  const float* bq  = (const float*)d_in[2];
  const float* Wk  = (const float*)d_in[3];
  const float* bk  = (const float*)d_in[4];
  const float* Wv  = (const float*)d_in[5];
  const float* bv  = (const float*)d_in[6];
  const float* g1  = (const float*)d_in[7];
  const float* be1 = (const float*)d_in[8];
  const float* W1  = (const float*)d_in[9];
  const float* bf1 = (const float*)d_in[10];
  const float* W2  = (const float*)d_in[11];
  const float* bf2 = (const float*)d_in[12];
  const float* g2  = (const float*)d_in[13];
  const float* be2 = (const float*)d_in[14];
  float* out = (float*)d_out;

  // Workspace layout (~196 MB): qbuf(64M) kbuf(64M) xhi(32M) xlo(32M) W(4M) sv...
  float* ws = (float*)d_ws;
  float* qbuf = ws;                                   // q -> corr -> attn
  float* kbuf = ws + FSZ;                             // k -> x1 fp32 -> (h2 input side)
  unsigned short* xhi = (unsigned short*)(ws + 2 * FSZ);  // x_hi, later x1b
  unsigned short* xlo = xhi + FSZ;                        // x_lo, later h1b
  unsigned short* wA = xlo + FSZ;                     // 1M bf16: W?t_hi / W1t
  unsigned short* wB = wA + (size_t)C_DIM * C_DIM;    // 1M bf16: W?t_lo / W2t
  float* sv = (float*)(wB + (size_t)C_DIM * C_DIM);   // [B*T]
  float* wvsum = sv + BT_DIM;                         // [C]
  float* bvsum = wvsum + C_DIM;                       // [1]

  const dim3 blk(256);
  const dim3 ggrid(C_DIM / 128, BT_DIM / 128);        // (8, 128)
  const dim3 tgrid(C_DIM / 32, C_DIM / 32);           // (32, 32)

  // x -> (hi, lo) bf16
  cvt_split_kernel<<<dim3(FSZ / 1024), blk, 0, stream>>>(x, xhi, xlo);

  // sv[b,t] = x[b,t,:] . rowsum(Wv) + sum(bv)   (v GEMM eliminated)
  wv_rowsum_kernel<<<dim3(C_DIM + 1), blk, 0, stream>>>(Wv, bv, wvsum, bvsum);
  sv_dot_kernel<<<dim3(BT_DIM), blk, 0, stream>>>(x, wvsum, bvsum, sv);

  // q = x @ Wq + bq (split precision)
  wtrans_kernel<<<tgrid, blk, 0, stream>>>(Wq, wA, wB, C_DIM, C_DIM);
  gemm_split_kernel<<<ggrid, blk, 0, stream>>>((const __bf16*)xhi, (const __bf16*)xlo,
                                               (const __bf16*)wA, (const __bf16*)wB,
                                               bq, qbuf, C_DIM, C_DIM);
  // k = x @ Wk + bk (split precision)
  wtrans_kernel<<<tgrid, blk, 0, stream>>>(Wk, wA, wB, C_DIM, C_DIM);
  gemm_split_kernel<<<ggrid, blk, 0, stream>>>((const __bf16*)xhi, (const __bf16*)xlo,
                                               (const __bf16*)wA, (const __bf16*)wB,
                                               bk, kbuf, C_DIM, C_DIM);

  // corr (in place over qbuf), then softmax*sv
  corr_fft_kernel<<<dim3(C_DIM / 2, B_DIM), blk, 0, stream>>>(qbuf, kbuf, qbuf);
  softmax_attn_kernel<<<dim3(C_DIM / 32, B_DIM), blk, 0, stream>>>(qbuf, sv);

  // x1 = LN(x + attn): fp32 -> kbuf, bf16 -> xhi region
  add_ln_kernel<<<dim3(BT_DIM), blk, 0, stream>>>(x, qbuf, g1, be1, kbuf, xhi);

  // FFN weights (plain bf16, transposed)
  wtrans_kernel<<<tgrid, blk, 0, stream>>>(W1, wA, nullptr, C_DIM, C_DIM);
  wtrans_kernel<<<tgrid, blk, 0, stream>>>(W2, wB, nullptr, C_DIM, C_DIM);

  // h1 = relu(x1 @ W1 + bf1) -> bf16 only (xlo region)
  gemm_bf16_kernel<<<ggrid, blk, 0, stream>>>((const __bf16*)xhi, (const __bf16*)wA,
                                              bf1, nullptr, xlo, C_DIM, C_DIM, 1);
  // h2 = h1 @ W2 + bf2 -> fp32 (qbuf)
  gemm_bf16_kernel<<<ggrid, blk, 0, stream>>>((const __bf16*)xlo, (const __bf16*)wB,
                                              bf2, qbuf, nullptr, C_DIM, C_DIM, 0);

  // out = LN(x1 + h2)
  add_ln_kernel<<<dim3(BT_DIM), blk, 0, stream>>>(kbuf, qbuf, g2, be2, out, nullptr);
}

// Round 3
// 761.972 us; speedup vs baseline: 3.6787x; 1.3264x over previous
//
#include <hip/hip_runtime.h>
#include <math.h>

// Problem constants (fixed-shape: B=8, T=2048, C=1024, fp32 in/out)
#define B_DIM 8
#define T_DIM 2048
#define C_DIM 1024
#define BT_DIM (B_DIM * T_DIM)                 // 16384 rows
#define FSZ ((size_t)BT_DIM * C_DIM)           // 16,777,216 elements per [B,T,C]
#define LN_EPS 1e-5f

typedef __bf16 bf16x8 __attribute__((ext_vector_type(8)));
typedef float f32x4 __attribute__((ext_vector_type(4)));

__device__ __forceinline__ unsigned short f2bf(float f) {
  __bf16 h = (__bf16)f;
  return __builtin_bit_cast(unsigned short, h);
}

// async global->LDS, 16 B per lane. LDS dest must be wave-uniform base + lane*16.
__device__ __forceinline__ void gld16(const void* g, void* l) {
  __builtin_amdgcn_global_load_lds(
      (const __attribute__((address_space(1))) unsigned int*)g,
      (__attribute__((address_space(3))) unsigned int*)l, 16, 0, 0);
}

// ---------------------------------------------------------------------------
// x fp32 -> (hi, lo) bf16 split: hi = bf16(x), lo = bf16(x - hi)
// ---------------------------------------------------------------------------
__global__ __launch_bounds__(256)
void cvt_split_kernel(const float* __restrict__ x, unsigned short* __restrict__ hi,
                      unsigned short* __restrict__ lo) {
  size_t idx = ((size_t)blockIdx.x * 256 + threadIdx.x) * 4;
  float4 v = *(const float4*)(x + idx);
  float f[4] = {v.x, v.y, v.z, v.w};
  unsigned short hv[4], lv[4];
#pragma unroll
  for (int i = 0; i < 4; i++) {
    __bf16 hb = (__bf16)f[i];
    hv[i] = __builtin_bit_cast(unsigned short, hb);
    lv[i] = f2bf(f[i] - (float)hb);
  }
  *(ushort4*)(hi + idx) = make_ushort4(hv[0], hv[1], hv[2], hv[3]);
  *(ushort4*)(lo + idx) = make_ushort4(lv[0], lv[1], lv[2], lv[3]);
}

// ---------------------------------------------------------------------------
// W [K,N] fp32 -> Wt [N,K] bf16 (hi only, or hi+lo split). 32x32 LDS tiles.
// ---------------------------------------------------------------------------
__global__ __launch_bounds__(256)
void wtrans_kernel(const float* __restrict__ W, unsigned short* __restrict__ Wt_hi,
                   unsigned short* __restrict__ Wt_lo, int K, int N) {
  __shared__ float tile[32][33];
  const int tid = threadIdx.x;
  const int tx = tid & 31, ty = tid >> 5;  // ty 0..7
  const int n0 = blockIdx.x * 32, k0 = blockIdx.y * 32;
#pragma unroll
  for (int i = 0; i < 4; i++) {
    int row = ty + i * 8;
    tile[row][tx] = W[(size_t)(k0 + row) * N + n0 + tx];
  }
  __syncthreads();
#pragma unroll
  for (int i = 0; i < 4; i++) {
    int row = ty + i * 8;                  // output n-row
    float v = tile[tx][row];               // W[k0+tx][n0+row]
    __bf16 hb = (__bf16)v;
    Wt_hi[(size_t)(n0 + row) * K + k0 + tx] = __builtin_bit_cast(unsigned short, hb);
    if (Wt_lo) Wt_lo[(size_t)(n0 + row) * K + k0 + tx] = f2bf(v - (float)hb);
  }
}

// ---------------------------------------------------------------------------
// wvsum[k] = sum_n Wv[k,n]  (blocks 0..K-1); block K reduces bv -> bvsum.
// ---------------------------------------------------------------------------
__global__ __launch_bounds__(256)
void wv_rowsum_kernel(const float* __restrict__ Wv, const float* __restrict__ bv,
                      float* __restrict__ wvsum, float* __restrict__ bvsum) {
  const int r = blockIdx.x;
  const int tid = threadIdx.x;
  const float* src = (r < C_DIM) ? (Wv + (size_t)r * C_DIM) : bv;
  float4 t4 = *(const float4*)(src + (tid << 2));
  float s = t4.x + t4.y + t4.z + t4.w;
#pragma unroll
  for (int off = 32; off > 0; off >>= 1) s += __shfl_down(s, off);
  __shared__ float ps[4];
  if ((tid & 63) == 0) ps[tid >> 6] = s;
  __syncthreads();
  if (tid == 0) {
    float v = ps[0] + ps[1] + ps[2] + ps[3];
    if (r < C_DIM) wvsum[r] = v; else bvsum[0] = v;
  }
}

// ---------------------------------------------------------------------------
// sv[r] = dot(x[r,:], wvsum) + bvsum   (replaces the whole v GEMM + rowsum)
// ---------------------------------------------------------------------------
__global__ __launch_bounds__(256)
void sv_dot_kernel(const float* __restrict__ x, const float* __restrict__ wvsum,
                   const float* __restrict__ bvsum, float* __restrict__ sv) {
  const int r = blockIdx.x;
  const int tid = threadIdx.x;
  float4 a = *(const float4*)(x + (size_t)r * C_DIM + (tid << 2));
  float4 w = *(const float4*)(wvsum + (tid << 2));
  float s = a.x * w.x + a.y * w.y + a.z * w.z + a.w * w.w;
#pragma unroll
  for (int off = 32; off > 0; off >>= 1) s += __shfl_down(s, off);
  __shared__ float ps[4];
  if ((tid & 63) == 0) ps[tid >> 6] = s;
  __syncthreads();
  if (tid == 0) sv[r] = ps[0] + ps[1] + ps[2] + ps[3] + bvsum[0];
}

// ---------------------------------------------------------------------------
// bf16 MFMA GEMM (m97 structure): Y[M,N] = A[M,K] @ Bt[N,K]^T + bias.
// 128x128 tile, BK=32, 256 thr = 4 waves in 2x2, 4x4 MFMA tiles/wave.
// Used for the FFN GEMMs (row-major [M,N] output, fp32 and/or bf16).
// ---------------------------------------------------------------------------
__global__ __launch_bounds__(256, 2)
void gemm_bf16_kernel(const __bf16* __restrict__ A, const __bf16* __restrict__ Bt,
                      const float* __restrict__ bias, float* Yf, unsigned short* Yb,
                      int K, int N, int do_relu) {
  __shared__ __align__(16) __bf16 As[128 * 32];
  __shared__ __align__(16) __bf16 Bs[128 * 32];
  const int tid = threadIdx.x;
  const int wave = tid >> 6, lane = tid & 63;
  const int wr = wave >> 1, wc = wave & 1;
  const int r15 = lane & 15, kq = lane >> 4;
  const int m0 = blockIdx.y * 128, n0 = blockIdx.x * 128;

  f32x4 acc[4][4] = {};

  for (int k0 = 0; k0 < K; k0 += 32) {
#pragma unroll
    for (int r = 0; r < 2; ++r) {
      int idx = r * 256 + tid;
      int row = idx >> 2;
      int ko = (idx & 3) ^ ((row >> 1) & 3);
      gld16(A + (size_t)(m0 + row) * K + k0 + ko * 8, &As[idx * 8]);
      gld16(Bt + (size_t)(n0 + row) * K + k0 + ko * 8, &Bs[idx * 8]);
    }
    __syncthreads();
    bf16x8 afr[4], bfr[4];
#pragma unroll
    for (int i = 0; i < 4; i++) {
      int ar = wr * 64 + i * 16 + r15;
      afr[i] = *(const bf16x8*)&As[(ar * 4 + (kq ^ ((ar >> 1) & 3))) * 8];
      int br = wc * 64 + i * 16 + r15;
      bfr[i] = *(const bf16x8*)&Bs[(br * 4 + (kq ^ ((br >> 1) & 3))) * 8];
    }
#pragma unroll
    for (int mi = 0; mi < 4; mi++)
#pragma unroll
      for (int ni = 0; ni < 4; ni++)
        acc[mi][ni] = __builtin_amdgcn_mfma_f32_16x16x32_bf16(afr[mi], bfr[ni], acc[mi][ni], 0, 0, 0);
    __syncthreads();
  }

  float bv[4];
#pragma unroll
  for (int ni = 0; ni < 4; ni++) bv[ni] = bias[n0 + wc * 64 + ni * 16 + r15];

#pragma unroll
  for (int mi = 0; mi < 4; mi++)
#pragma unroll
    for (int ni = 0; ni < 4; ni++) {
      const int n = n0 + wc * 64 + ni * 16 + r15;
#pragma unroll
      for (int r = 0; r < 4; r++) {
        const int m = m0 + wr * 64 + mi * 16 + kq * 4 + r;
        float v = acc[mi][ni][r] + bv[ni];
        if (do_relu) v = fmaxf(v, 0.f);
        if (Yf) Yf[(size_t)m * N + n] = v;
        if (Yb) Yb[(size_t)m * N + n] = f2bf(v);
      }
    }
}

// ---------------------------------------------------------------------------
// Split-precision GEMM with TRANSPOSED output: Yt[B,C,T], fp32.
// Yt[b][n][t] = sum_k (Ahi+Alo)[m,k] * (Bhi+Blo)[n,k] + bias[n],  m = b*T + t.
// 3 MFMA passes: hi*hi + hi*lo + lo*hi. The MFMA C-layout makes the
// transposed store a single float4 per fragment (t contiguous over reg idx).
// ---------------------------------------------------------------------------
__global__ __launch_bounds__(256, 2)
void gemm_splitT_kernel(const __bf16* __restrict__ Ahi, const __bf16* __restrict__ Alo,
                        const __bf16* __restrict__ Bhi, const __bf16* __restrict__ Blo,
                        const float* __restrict__ bias, float* __restrict__ Yt,
                        int K, int N) {
  __shared__ __align__(16) __bf16 Ash[128 * 32];
  __shared__ __align__(16) __bf16 Asl[128 * 32];
  __shared__ __align__(16) __bf16 Bsh[128 * 32];
  __shared__ __align__(16) __bf16 Bsl[128 * 32];
  const int tid = threadIdx.x;
  const int wave = tid >> 6, lane = tid & 63;
  const int wr = wave >> 1, wc = wave & 1;
  const int r15 = lane & 15, kq = lane >> 4;
  const int m0 = blockIdx.y * 128, n0 = blockIdx.x * 128;

  f32x4 acc[4][4] = {};

  for (int k0 = 0; k0 < K; k0 += 32) {
#pragma unroll
    for (int r = 0; r < 2; ++r) {
      int idx = r * 256 + tid;
      int row = idx >> 2;
      int ko = (idx & 3) ^ ((row >> 1) & 3);
      size_t ga = (size_t)(m0 + row) * K + k0 + ko * 8;
      size_t gb = (size_t)(n0 + row) * K + k0 + ko * 8;
      gld16(Ahi + ga, &Ash[idx * 8]);
      gld16(Alo + ga, &Asl[idx * 8]);
      gld16(Bhi + gb, &Bsh[idx * 8]);
      gld16(Blo + gb, &Bsl[idx * 8]);
    }
    __syncthreads();
    bf16x8 ah[4], al[4], bh[4], bl[4];
#pragma unroll
    for (int i = 0; i < 4; i++) {
      int ar = wr * 64 + i * 16 + r15;
      int as = (ar * 4 + (kq ^ ((ar >> 1) & 3))) * 8;
      ah[i] = *(const bf16x8*)&Ash[as];
      al[i] = *(const bf16x8*)&Asl[as];
      int br = wc * 64 + i * 16 + r15;
      int bs = (br * 4 + (kq ^ ((br >> 1) & 3))) * 8;
      bh[i] = *(const bf16x8*)&Bsh[bs];
      bl[i] = *(const bf16x8*)&Bsl[bs];
    }
#pragma unroll
    for (int mi = 0; mi < 4; mi++)
#pragma unroll
      for (int ni = 0; ni < 4; ni++) {
        f32x4 c = acc[mi][ni];
        c = __builtin_amdgcn_mfma_f32_16x16x32_bf16(ah[mi], bh[ni], c, 0, 0, 0);
        c = __builtin_amdgcn_mfma_f32_16x16x32_bf16(ah[mi], bl[ni], c, 0, 0, 0);
        c = __builtin_amdgcn_mfma_f32_16x16x32_bf16(al[mi], bh[ni], c, 0, 0, 0);
        acc[mi][ni] = c;
      }
    __syncthreads();
  }

  float bv[4];
#pragma unroll
  for (int ni = 0; ni < 4; ni++) bv[ni] = bias[n0 + wc * 64 + ni * 16 + r15];

#pragma unroll
  for (int mi = 0; mi < 4; mi++) {
    const int mbase = m0 + wr * 64 + mi * 16 + kq * 4;  // 4 consecutive m
    const int bb = mbase >> 11;                          // batch (T=2048)
    const int t = mbase & (T_DIM - 1);
#pragma unroll
    for (int ni = 0; ni < 4; ni++) {
      const int n = n0 + wc * 64 + ni * 16 + r15;
      float4 o = make_float4(acc[mi][ni][0] + bv[ni], acc[mi][ni][1] + bv[ni],
                             acc[mi][ni][2] + bv[ni], acc[mi][ni][3] + bv[ni]);
      *(float4*)(Yt + ((size_t)bb * C_DIM + n) * T_DIM + t) = o;
    }
  }
}

// ---------------------------------------------------------------------------
// 2048-point complex Stockham FFT in LDS, twiddles from a 512-entry
// quarter-wave table (tw[j] = (cos, sin)(2*pi*j/2048), j<512; reflection for
// j>=512: theta += pi/2 -> (c,s) = (-s', c')).  sgn=-1 fwd, +1 inv.
// ---------------------------------------------------------------------------
__device__ float2* fft2048(float2* a, float2* b, const float2* tw, int tid, float sgn) {
  float2* src = a;
  float2* dst = b;
#pragma unroll 1
  for (int s = 0; s < 11; s++) {
    const int m = 1 << s;
#pragma unroll 1
    for (int i = tid; i < 1024; i += 256) {
      const int kk = i & (m - 1);
      const int j = i - kk;            // in [0,1024)
      float2 twv = tw[j & 511];
      float cw = (j & 512) ? -twv.y : twv.x;
      float sw = ((j & 512) ? twv.x : twv.y) * sgn;
      float2 c0 = src[i];
      float2 c1 = src[i + 1024];
      float dx = c0.x - c1.x, dy = c0.y - c1.y;
      const int o0 = (i << 1) - kk;
      dst[o0] = make_float2(c0.x + c1.x, c0.y + c1.y);
      dst[o0 + m] = make_float2(cw * dx - sw * dy, cw * dy + sw * dx);
    }
    __syncthreads();
    float2* t = src; src = dst; dst = t;
  }
  return src;
}

// corrT[b,c,:] = irfft(rfft(qT)*conj(rfft(kT))) along T. Layout [B,C,T]:
// fully contiguous 8 KB row reads/writes. 2 channels/block packed as complex.
__global__ __launch_bounds__(256)
void corr_fft_kernel(const float* qT, const float* kT, float* corrT) {
  __shared__ float2 bA[2048];
  __shared__ float2 bB[2048];
  __shared__ float2 bC[2048];
  __shared__ float2 tw[512];
  const int tid = threadIdx.x;
  const int b = blockIdx.y;
  const int c0 = blockIdx.x * 2;
  const float* q0 = qT + ((size_t)b * C_DIM + c0) * T_DIM;
  const float* k0p = kT + ((size_t)b * C_DIM + c0) * T_DIM;

  // twiddle table (quarter wave)
#pragma unroll 1
  for (int j = tid; j < 512; j += 256) {
    float sA, cA;
    __sincosf((float)j * (6.283185307179586f / 2048.0f), &sA, &cA);
    tw[j] = make_float2(cA, sA);
  }

  // load packed zq = q_c0 + i*q_{c0+1} (two contiguous rows)
#pragma unroll 1
  for (int t = tid; t < T_DIM; t += 256)
    bA[t] = make_float2(q0[t], q0[t + T_DIM]);
  __syncthreads();
  float2* FQ = fft2048(bA, bB, tw, tid, -1.0f);   // -> bB

#pragma unroll 1
  for (int t = tid; t < T_DIM; t += 256)
    bA[t] = make_float2(k0p[t], k0p[t + T_DIM]);
  __syncthreads();
  float2* FK = fft2048(bA, bC, tw, tid, -1.0f);   // -> bC (bB untouched)

  // pointwise: unpack A/B spectra, cross-spectra G,H, repack W = G + i*H -> bA
#pragma unroll 1
  for (int f = tid; f < T_DIM; f += 256) {
    const int f2 = (T_DIM - f) & (T_DIM - 1);
    float2 Zq = FQ[f], Zq2 = FQ[f2];
    float2 Zk = FK[f], Zk2 = FK[f2];
    float2 Aq = make_float2(0.5f * (Zq.x + Zq2.x), 0.5f * (Zq.y - Zq2.y));
    float2 Dq = make_float2(Zq.x - Zq2.x, Zq.y + Zq2.y);
    float2 Bq = make_float2(0.5f * Dq.y, -0.5f * Dq.x);
    float2 Ak = make_float2(0.5f * (Zk.x + Zk2.x), 0.5f * (Zk.y - Zk2.y));
    float2 Dk = make_float2(Zk.x - Zk2.x, Zk.y + Zk2.y);
    float2 Bk = make_float2(0.5f * Dk.y, -0.5f * Dk.x);
    float2 G = make_float2(Aq.x * Ak.x + Aq.y * Ak.y, Aq.y * Ak.x - Aq.x * Ak.y);
    float2 H = make_float2(Bq.x * Bk.x + Bq.y * Bk.y, Bq.y * Bk.x - Bq.x * Bk.y);
    bA[f] = make_float2(G.x - H.y, G.y + H.x);
  }
  __syncthreads();
  float2* OUT = fft2048(bA, bB, tw, tid, +1.0f);  // -> bB

  float* o0 = corrT + ((size_t)b * C_DIM + c0) * T_DIM;
  const float sc = 1.0f / 2048.0f;
#pragma unroll 1
  for (int t = tid; t < T_DIM; t += 256) {
    float2 o = OUT[t];
    o0[t] = o.x * sc;
    o0[t + T_DIM] = o.y * sc;
  }
}

// ---------------------------------------------------------------------------
// Per-(b,c) softmax stats over T: M = max, I = 1/sum(exp(v-M)). [B,C,T] rows.
// ---------------------------------------------------------------------------
__global__ __launch_bounds__(256)
void softmax_ms_kernel(const float* __restrict__ corrT, float* __restrict__ Mv,
                       float* __restrict__ Iv) {
  const int b = blockIdx.y, c = blockIdx.x;
  const int tid = threadIdx.x;
  const float* row = corrT + ((size_t)b * C_DIM + c) * T_DIM;
  float4 v0 = ((const float4*)row)[tid];
  float4 v1 = ((const float4*)row)[tid + 256];
  float m = fmaxf(fmaxf(fmaxf(v0.x, v0.y), fmaxf(v0.z, v0.w)),
                  fmaxf(fmaxf(v1.x, v1.y), fmaxf(v1.z, v1.w)));
#pragma unroll
  for (int off = 32; off > 0; off >>= 1) m = fmaxf(m, __shfl_down(m, off));
  __shared__ float pm[4], ps[4];
  if ((tid & 63) == 0) pm[tid >> 6] = m;
  __syncthreads();
  const float M = fmaxf(fmaxf(pm[0], pm[1]), fmaxf(pm[2], pm[3]));
  float s = __expf(v0.x - M) + __expf(v0.y - M) + __expf(v0.z - M) + __expf(v0.w - M) +
            __expf(v1.x - M) + __expf(v1.y - M) + __expf(v1.z - M) + __expf(v1.w - M);
#pragma unroll
  for (int off = 32; off > 0; off >>= 1) s += __shfl_down(s, off);
  if ((tid & 63) == 0) ps[tid >> 6] = s;
  __syncthreads();
  if (tid == 0) {
    float S = ps[0] + ps[1] + ps[2] + ps[3];
    Mv[(size_t)b * C_DIM + c] = M;
    Iv[(size_t)b * C_DIM + c] = 1.0f / S;
  }
}

// ---------------------------------------------------------------------------
// Fused: attn[b,t,c] = exp(corrT[b,c,t]-M[b,c]) * I[b,c] * sv[b,t],
// with 32x32 LDS tiled transpose [B,C,T] -> [B,T,C].
// ---------------------------------------------------------------------------
__global__ __launch_bounds__(256)
void attn_transpose_kernel(const float* __restrict__ corrT, const float* __restrict__ Mv,
                           const float* __restrict__ Iv, const float* __restrict__ sv,
                           float* __restrict__ attn) {
  __shared__ float tile[32][33];
  const int tid = threadIdx.x;
  const int tx = tid & 31, ty = tid >> 5;   // ty 0..7
  const int t0 = blockIdx.x * 32, c0 = blockIdx.y * 32, b = blockIdx.z;
  const float svv = sv[(size_t)b * T_DIM + t0 + tx];
#pragma unroll
  for (int i = 0; i < 4; i++) {
    const int c = c0 + ty + i * 8;
    const float M = Mv[(size_t)b * C_DIM + c];
    const float I = Iv[(size_t)b * C_DIM + c];
    float v = corrT[((size_t)b * C_DIM + c) * T_DIM + t0 + tx];
    tile[ty + i * 8][tx] = __expf(v - M) * I * svv;
  }
  __syncthreads();
#pragma unroll
  for (int i = 0; i < 4; i++) {
    const int t = t0 + ty + i * 8;
    attn[((size_t)b * T_DIM + t) * C_DIM + c0 + tx] = tile[tx][ty + i * 8];
  }
}

// ---------------------------------------------------------------------------
// out = LayerNorm(A + Bv) * g + be; optional bf16 copy of out.
// ---------------------------------------------------------------------------
__global__ __launch_bounds__(256)
void add_ln_kernel(const float* __restrict__ A, const float* __restrict__ Bv,
                   const float* __restrict__ g, const float* __restrict__ be,
                   float* __restrict__ outf, unsigned short* outb) {
  const int r = blockIdx.x;
  const int tid = threadIdx.x;
  const size_t base = (size_t)r * C_DIM + (tid << 2);
  float4 a = *(const float4*)(A + base);
  float4 b = *(const float4*)(Bv + base);
  float x0 = a.x + b.x, x1 = a.y + b.y, x2 = a.z + b.z, x3 = a.w + b.w;
  float s = x0 + x1 + x2 + x3;
  float s2 = x0 * x0 + x1 * x1 + x2 * x2 + x3 * x3;
#pragma unroll
  for (int off = 32; off > 0; off >>= 1) {
    s += __shfl_down(s, off);
    s2 += __shfl_down(s2, off);
  }
  __shared__ float ps[4], ps2[4];
  if ((tid & 63) == 0) { ps[tid >> 6] = s; ps2[tid >> 6] = s2; }
  __syncthreads();
  float S = ps[0] + ps[1] + ps[2] + ps[3];
  float S2 = ps2[0] + ps2[1] + ps2[2] + ps2[3];
  const float mu = S * (1.0f / C_DIM);
  const float var = S2 * (1.0f / C_DIM) - mu * mu;
  const float rs = rsqrtf(var + LN_EPS);
  float4 gv = *(const float4*)(g + (tid << 2));
  float4 bev = *(const float4*)(be + (tid << 2));
  float o0 = (x0 - mu) * rs * gv.x + bev.x;
  float o1 = (x1 - mu) * rs * gv.y + bev.y;
  float o2 = (x2 - mu) * rs * gv.z + bev.z;
  float o3 = (x3 - mu) * rs * gv.w + bev.w;
  *(float4*)(outf + base) = make_float4(o0, o1, o2, o3);
  if (outb) *(ushort4*)(outb + base) = make_ushort4(f2bf(o0), f2bf(o1), f2bf(o2), f2bf(o3));
}

// ---------------------------------------------------------------------------
extern "C" void kernel_launch(void* const* d_in, const int* in_sizes, int n_in,
                              void* d_out, int out_size, void* d_ws, size_t ws_size,
                              hipStream_t stream) {
  const float* x   = (const float*)d_in[0];
  const float* Wq  = (const float*)d_in[1];
  const float* bq  = (const float*)d_in[2];
  const float* Wk  = (const float*)d_in[3];
  const float* bk  = (const float*)d_in[4];
  const float* Wv  = (const float*)d_in[5];
  const float* bv  = (const float*)d_in[6];
  const float* g1  = (const float*)d_in[7];
  const float* be1 = (const float*)d_in[8];
  const float* W1  = (const float*)d_in[9];
  const float* bf1 = (const float*)d_in[10];
  const float* W2  = (const float*)d_in[11];
  const float* bf2 = (const float*)d_in[12];
  const float* g2  = (const float*)d_in[13];
  const float* be2 = (const float*)d_in[14];
  float* out = (float*)d_out;

  // Workspace: qbuf(64M) kbuf(64M) xhi(32M) xlo(32M) wA(2M) wB(2M) + small
  float* ws = (float*)d_ws;
  float* qbuf = ws;                                   // qT -> corrT -> x1 fp32
  float* kbuf = ws + FSZ;                             // kT -> attn[B,T,C] -> h2 fp32
  unsigned short* xhi = (unsigned short*)(ws + 2 * FSZ);  // x_hi, later x1 bf16
  unsigned short* xlo = xhi + FSZ;                        // x_lo, later h1 bf16
  unsigned short* wA = xlo + FSZ;                     // 1M bf16
  unsigned short* wB = wA + (size_t)C_DIM * C_DIM;    // 1M bf16
  float* sv = (float*)(wB + (size_t)C_DIM * C_DIM);   // [B*T]
  float* wvsum = sv + BT_DIM;                         // [C]
  float* bvsum = wvsum + C_DIM;                       // [1]
  float* Mv = bvsum + 1;                              // [B*C]
  float* Iv = Mv + (size_t)B_DIM * C_DIM;             // [B*C]

  const dim3 blk(256);
  const dim3 ggrid(C_DIM / 128, BT_DIM / 128);        // (8, 128)
  const dim3 tgrid(C_DIM / 32, C_DIM / 32);           // (32, 32)

  // x -> (hi, lo) bf16
  cvt_split_kernel<<<dim3(FSZ / 1024), blk, 0, stream>>>(x, xhi, xlo);

  // sv[b,t] = x[b,t,:] . rowsum(Wv) + sum(bv)   (v GEMM eliminated)
  wv_rowsum_kernel<<<dim3(C_DIM + 1), blk, 0, stream>>>(Wv, bv, wvsum, bvsum);
  sv_dot_kernel<<<dim3(BT_DIM), blk, 0, stream>>>(x, wvsum, bvsum, sv);

  // qT = (x @ Wq + bq)^T per batch  (split precision, [B,C,T] output)
  wtrans_kernel<<<tgrid, blk, 0, stream>>>(Wq, wA, wB, C_DIM, C_DIM);
  gemm_splitT_kernel<<<ggrid, blk, 0, stream>>>((const __bf16*)xhi, (const __bf16*)xlo,
                                                (const __bf16*)wA, (const __bf16*)wB,
                                                bq, qbuf, C_DIM, C_DIM);
  // kT likewise
  wtrans_kernel<<<tgrid, blk, 0, stream>>>(Wk, wA, wB, C_DIM, C_DIM);
  gemm_splitT_kernel<<<ggrid, blk, 0, stream>>>((const __bf16*)xhi, (const __bf16*)xlo,
                                                (const __bf16*)wA, (const __bf16*)wB,
                                                bk, kbuf, C_DIM, C_DIM);

  // corrT (in place over qbuf), contiguous rows
  corr_fft_kernel<<<dim3(C_DIM / 2, B_DIM), blk, 0, stream>>>(qbuf, kbuf, qbuf);

  // softmax stats per (b,c), then fused exp*scale*sv + transpose -> attn [B,T,C]
  softmax_ms_kernel<<<dim3(C_DIM, B_DIM), blk, 0, stream>>>(qbuf, Mv, Iv);
  attn_transpose_kernel<<<dim3(T_DIM / 32, C_DIM / 32, B_DIM), blk, 0, stream>>>(
      qbuf, Mv, Iv, sv, kbuf);

  // x1 = LN(x + attn): fp32 -> qbuf, bf16 -> xhi region
  add_ln_kernel<<<dim3(BT_DIM), blk, 0, stream>>>(x, kbuf, g1, be1, qbuf, xhi);

  // FFN weights (plain bf16, transposed)
  wtrans_kernel<<<tgrid, blk, 0, stream>>>(W1, wA, nullptr, C_DIM, C_DIM);
  wtrans_kernel<<<tgrid, blk, 0, stream>>>(W2, wB, nullptr, C_DIM, C_DIM);

  // h1 = relu(x1 @ W1 + bf1) -> bf16 only (xlo region)
  gemm_bf16_kernel<<<ggrid, blk, 0, stream>>>((const __bf16*)xhi, (const __bf16*)wA,
                                              bf1, nullptr, xlo, C_DIM, C_DIM, 1);
  // h2 = h1 @ W2 + bf2 -> fp32 (kbuf)
  gemm_bf16_kernel<<<ggrid, blk, 0, stream>>>((const __bf16*)xlo, (const __bf16*)wB,
                                              bf2, kbuf, nullptr, C_DIM, C_DIM, 0);

  // out = LN(x1 + h2)
  add_ln_kernel<<<dim3(BT_DIM), blk, 0, stream>>>(qbuf, kbuf, g2, be2, out, nullptr);
}

// Round 4
// 687.949 us; speedup vs baseline: 4.0745x; 1.1076x over previous
//
#include <hip/hip_runtime.h>
#include <math.h>

// Problem constants (fixed-shape: B=8, T=2048, C=1024, fp32 in/out)
#define B_DIM 8
#define T_DIM 2048
#define C_DIM 1024
#define BT_DIM (B_DIM * T_DIM)                 // 16384 rows
#define FSZ ((size_t)BT_DIM * C_DIM)           // 16,777,216 elements per [B,T,C]
#define LN_EPS 1e-5f

typedef __bf16 bf16x8 __attribute__((ext_vector_type(8)));
typedef _Float16 f16x8 __attribute__((ext_vector_type(8)));
typedef float f32x4 __attribute__((ext_vector_type(4)));

__device__ __forceinline__ unsigned short f2bf(float f) {
  __bf16 h = (__bf16)f;
  return __builtin_bit_cast(unsigned short, h);
}
__device__ __forceinline__ unsigned short f2h(float f) {
  _Float16 h = (_Float16)f;
  return __builtin_bit_cast(unsigned short, h);
}

// async global->LDS, 16 B per lane. LDS dest must be wave-uniform base + lane*16.
__device__ __forceinline__ void gld16(const void* g, void* l) {
  __builtin_amdgcn_global_load_lds(
      (const __attribute__((address_space(1))) unsigned int*)g,
      (__attribute__((address_space(3))) unsigned int*)l, 16, 0, 0);
}

// ---------------------------------------------------------------------------
// x fp32 -> (hi, lo) f16 split: hi = f16(x), lo = f16(x - hi)  (~21 mant bits)
// ---------------------------------------------------------------------------
__global__ __launch_bounds__(256)
void cvt_split_f16_kernel(const float* __restrict__ x, unsigned short* __restrict__ hi,
                          unsigned short* __restrict__ lo) {
  size_t idx = ((size_t)blockIdx.x * 256 + threadIdx.x) * 4;
  float4 v = *(const float4*)(x + idx);
  float f[4] = {v.x, v.y, v.z, v.w};
  unsigned short hv[4], lv[4];
#pragma unroll
  for (int i = 0; i < 4; i++) {
    _Float16 hb = (_Float16)f[i];
    hv[i] = __builtin_bit_cast(unsigned short, hb);
    lv[i] = f2h(f[i] - (float)hb);
  }
  *(ushort4*)(hi + idx) = make_ushort4(hv[0], hv[1], hv[2], hv[3]);
  *(ushort4*)(lo + idx) = make_ushort4(lv[0], lv[1], lv[2], lv[3]);
}

// ---------------------------------------------------------------------------
// W [K,N] fp32 -> Wt [N,K] f16 (hi only). 32x32 LDS tiles.
// ---------------------------------------------------------------------------
__global__ __launch_bounds__(256)
void wtrans_f16_kernel(const float* __restrict__ W, unsigned short* __restrict__ Wt,
                       int K, int N) {
  __shared__ float tile[32][33];
  const int tid = threadIdx.x;
  const int tx = tid & 31, ty = tid >> 5;
  const int n0 = blockIdx.x * 32, k0 = blockIdx.y * 32;
#pragma unroll
  for (int i = 0; i < 4; i++) {
    int row = ty + i * 8;
    tile[row][tx] = W[(size_t)(k0 + row) * N + n0 + tx];
  }
  __syncthreads();
#pragma unroll
  for (int i = 0; i < 4; i++) {
    int row = ty + i * 8;
    Wt[(size_t)(n0 + row) * K + k0 + tx] = f2h(tile[tx][row]);
  }
}

// ---------------------------------------------------------------------------
// W [K,N] fp32 -> Wt [N,K] bf16 (hi only). For the FFN weights.
// ---------------------------------------------------------------------------
__global__ __launch_bounds__(256)
void wtrans_kernel(const float* __restrict__ W, unsigned short* __restrict__ Wt,
                   int K, int N) {
  __shared__ float tile[32][33];
  const int tid = threadIdx.x;
  const int tx = tid & 31, ty = tid >> 5;
  const int n0 = blockIdx.x * 32, k0 = blockIdx.y * 32;
#pragma unroll
  for (int i = 0; i < 4; i++) {
    int row = ty + i * 8;
    tile[row][tx] = W[(size_t)(k0 + row) * N + n0 + tx];
  }
  __syncthreads();
#pragma unroll
  for (int i = 0; i < 4; i++) {
    int row = ty + i * 8;
    Wt[(size_t)(n0 + row) * K + k0 + tx] = f2bf(tile[tx][row]);
  }
}

// ---------------------------------------------------------------------------
// wvsum[k] = sum_n Wv[k,n]  (blocks 0..K-1); block K reduces bv -> bvsum.
// ---------------------------------------------------------------------------
__global__ __launch_bounds__(256)
void wv_rowsum_kernel(const float* __restrict__ Wv, const float* __restrict__ bv,
                      float* __restrict__ wvsum, float* __restrict__ bvsum) {
  const int r = blockIdx.x;
  const int tid = threadIdx.x;
  const float* src = (r < C_DIM) ? (Wv + (size_t)r * C_DIM) : bv;
  float4 t4 = *(const float4*)(src + (tid << 2));
  float s = t4.x + t4.y + t4.z + t4.w;
#pragma unroll
  for (int off = 32; off > 0; off >>= 1) s += __shfl_down(s, off);
  __shared__ float ps[4];
  if ((tid & 63) == 0) ps[tid >> 6] = s;
  __syncthreads();
  if (tid == 0) {
    float v = ps[0] + ps[1] + ps[2] + ps[3];
    if (r < C_DIM) wvsum[r] = v; else bvsum[0] = v;
  }
}

// ---------------------------------------------------------------------------
// sv[r] = dot(x[r,:], wvsum) + bvsum   (replaces the whole v GEMM + rowsum)
// ---------------------------------------------------------------------------
__global__ __launch_bounds__(256)
void sv_dot_kernel(const float* __restrict__ x, const float* __restrict__ wvsum,
                   const float* __restrict__ bvsum, float* __restrict__ sv) {
  const int r = blockIdx.x;
  const int tid = threadIdx.x;
  float4 a = *(const float4*)(x + (size_t)r * C_DIM + (tid << 2));
  float4 w = *(const float4*)(wvsum + (tid << 2));
  float s = a.x * w.x + a.y * w.y + a.z * w.z + a.w * w.w;
#pragma unroll
  for (int off = 32; off > 0; off >>= 1) s += __shfl_down(s, off);
  __shared__ float ps[4];
  if ((tid & 63) == 0) ps[tid >> 6] = s;
  __syncthreads();
  if (tid == 0) sv[r] = ps[0] + ps[1] + ps[2] + ps[3] + bvsum[0];
}

// ---------------------------------------------------------------------------
// bf16 MFMA GEMM (m97 structure): Y[M,N] = A[M,K] @ Bt[N,K]^T + bias.
// 128x128 tile, BK=32, 4 waves 2x2, 4x4 MFMA tiles/wave. FFN GEMMs.
// ---------------------------------------------------------------------------
__global__ __launch_bounds__(256, 2)
void gemm_bf16_kernel(const __bf16* __restrict__ A, const __bf16* __restrict__ Bt,
                      const float* __restrict__ bias, float* Yf, unsigned short* Yb,
                      int K, int N, int do_relu) {
  __shared__ __align__(16) __bf16 As[128 * 32];
  __shared__ __align__(16) __bf16 Bs[128 * 32];
  const int tid = threadIdx.x;
  const int wave = tid >> 6, lane = tid & 63;
  const int wr = wave >> 1, wc = wave & 1;
  const int r15 = lane & 15, kq = lane >> 4;
  const int m0 = blockIdx.y * 128, n0 = blockIdx.x * 128;

  f32x4 acc[4][4] = {};

  for (int k0 = 0; k0 < K; k0 += 32) {
#pragma unroll
    for (int r = 0; r < 2; ++r) {
      int idx = r * 256 + tid;
      int row = idx >> 2;
      int ko = (idx & 3) ^ ((row >> 1) & 3);
      gld16(A + (size_t)(m0 + row) * K + k0 + ko * 8, &As[idx * 8]);
      gld16(Bt + (size_t)(n0 + row) * K + k0 + ko * 8, &Bs[idx * 8]);
    }
    __syncthreads();
    bf16x8 afr[4], bfr[4];
#pragma unroll
    for (int i = 0; i < 4; i++) {
      int ar = wr * 64 + i * 16 + r15;
      afr[i] = *(const bf16x8*)&As[(ar * 4 + (kq ^ ((ar >> 1) & 3))) * 8];
      int br = wc * 64 + i * 16 + r15;
      bfr[i] = *(const bf16x8*)&Bs[(br * 4 + (kq ^ ((br >> 1) & 3))) * 8];
    }
#pragma unroll
    for (int mi = 0; mi < 4; mi++)
#pragma unroll
      for (int ni = 0; ni < 4; ni++)
        acc[mi][ni] = __builtin_amdgcn_mfma_f32_16x16x32_bf16(afr[mi], bfr[ni], acc[mi][ni], 0, 0, 0);
    __syncthreads();
  }

  float bv[4];
#pragma unroll
  for (int ni = 0; ni < 4; ni++) bv[ni] = bias[n0 + wc * 64 + ni * 16 + r15];

#pragma unroll
  for (int mi = 0; mi < 4; mi++)
#pragma unroll
    for (int ni = 0; ni < 4; ni++) {
      const int n = n0 + wc * 64 + ni * 16 + r15;
#pragma unroll
      for (int r = 0; r < 4; r++) {
        const int m = m0 + wr * 64 + mi * 16 + kq * 4 + r;
        float v = acc[mi][ni][r] + bv[ni];
        if (do_relu) v = fmaxf(v, 0.f);
        if (Yf) Yf[(size_t)m * N + n] = v;
        if (Yb) Yb[(size_t)m * N + n] = f2bf(v);
      }
    }
}

// ---------------------------------------------------------------------------
// f16 2-pass split GEMM with TRANSPOSED output: Yt[B,C,T] fp32.
// Yt[b][n][t] = sum_k (Ahi+Alo)[m,k] * Bhi[n,k] + bias[n],  m = b*T + t.
// A covers ~21 mantissa bits (f16 hi+lo); B truncation 2^-11 rel is harmless.
// ---------------------------------------------------------------------------
__global__ __launch_bounds__(256, 2)
void gemm_splitT_f16_kernel(const _Float16* __restrict__ Ahi, const _Float16* __restrict__ Alo,
                            const _Float16* __restrict__ Bhi, const float* __restrict__ bias,
                            float* __restrict__ Yt, int K, int N) {
  __shared__ __align__(16) _Float16 Ash[128 * 32];
  __shared__ __align__(16) _Float16 Asl[128 * 32];
  __shared__ __align__(16) _Float16 Bsh[128 * 32];
  const int tid = threadIdx.x;
  const int wave = tid >> 6, lane = tid & 63;
  const int wr = wave >> 1, wc = wave & 1;
  const int r15 = lane & 15, kq = lane >> 4;
  const int m0 = blockIdx.y * 128, n0 = blockIdx.x * 128;

  f32x4 acc[4][4] = {};

  for (int k0 = 0; k0 < K; k0 += 32) {
#pragma unroll
    for (int r = 0; r < 2; ++r) {
      int idx = r * 256 + tid;
      int row = idx >> 2;
      int ko = (idx & 3) ^ ((row >> 1) & 3);
      size_t ga = (size_t)(m0 + row) * K + k0 + ko * 8;
      size_t gb = (size_t)(n0 + row) * K + k0 + ko * 8;
      gld16(Ahi + ga, &Ash[idx * 8]);
      gld16(Alo + ga, &Asl[idx * 8]);
      gld16(Bhi + gb, &Bsh[idx * 8]);
    }
    __syncthreads();
    f16x8 ah[4], al[4], bh[4];
#pragma unroll
    for (int i = 0; i < 4; i++) {
      int ar = wr * 64 + i * 16 + r15;
      int as = (ar * 4 + (kq ^ ((ar >> 1) & 3))) * 8;
      ah[i] = *(const f16x8*)&Ash[as];
      al[i] = *(const f16x8*)&Asl[as];
      int br = wc * 64 + i * 16 + r15;
      int bs = (br * 4 + (kq ^ ((br >> 1) & 3))) * 8;
      bh[i] = *(const f16x8*)&Bsh[bs];
    }
#pragma unroll
    for (int mi = 0; mi < 4; mi++)
#pragma unroll
      for (int ni = 0; ni < 4; ni++) {
        f32x4 c = acc[mi][ni];
        c = __builtin_amdgcn_mfma_f32_16x16x32_f16(ah[mi], bh[ni], c, 0, 0, 0);
        c = __builtin_amdgcn_mfma_f32_16x16x32_f16(al[mi], bh[ni], c, 0, 0, 0);
        acc[mi][ni] = c;
      }
    __syncthreads();
  }

  float bv[4];
#pragma unroll
  for (int ni = 0; ni < 4; ni++) bv[ni] = bias[n0 + wc * 64 + ni * 16 + r15];

#pragma unroll
  for (int mi = 0; mi < 4; mi++) {
    const int mbase = m0 + wr * 64 + mi * 16 + kq * 4;  // 4 consecutive m
    const int bb = mbase >> 11;                          // batch (T=2048)
    const int t = mbase & (T_DIM - 1);
#pragma unroll
    for (int ni = 0; ni < 4; ni++) {
      const int n = n0 + wc * 64 + ni * 16 + r15;
      float4 o = make_float4(acc[mi][ni][0] + bv[ni], acc[mi][ni][1] + bv[ni],
                             acc[mi][ni][2] + bv[ni], acc[mi][ni][3] + bv[ni]);
      *(float4*)(Yt + ((size_t)bb * C_DIM + n) * T_DIM + t) = o;
    }
  }
}

// ---------------------------------------------------------------------------
// 2048-pt complex Stockham FFT, radix-4 (5 stages) + twiddle-free radix-2.
// tw[j] = (cos,sin)(2*pi*j/2048), j in [0,512) — all radix-4 twiddle indices
// are < 512, no reflection needed. w2 = w1^2, w3 = w1^3 computed in-register.
// sgn=-1 fwd, +1 inv (unnormalized). Result lands back in buffer `a`.
// ---------------------------------------------------------------------------
__device__ float2* fft2048_r4(float2* a, float2* b, const float2* tw, int tid, float sgn) {
  float2* src = a;
  float2* dst = b;
#pragma unroll 1
  for (int s = 0; s < 5; s++) {
    const int m = 1 << (2 * s);
#pragma unroll 1
    for (int i = tid; i < 512; i += 256) {
      const int k = i & (m - 1);
      const int j = i - k;               // multiple of m, in [0,512)
      float2 t1 = tw[j];
      const float c1 = t1.x, s1 = t1.y * sgn;
      const float c2 = c1 * c1 - s1 * s1, s2 = 2.f * c1 * s1;
      const float c3 = c2 * c1 - s2 * s1, s3 = c2 * s1 + s2 * c1;
      float2 A = src[i], Bv = src[i + 512], Cv = src[i + 1024], Dv = src[i + 1536];
      float2 apc = make_float2(A.x + Cv.x, A.y + Cv.y);
      float2 amc = make_float2(A.x - Cv.x, A.y - Cv.y);
      float2 bpd = make_float2(Bv.x + Dv.x, Bv.y + Dv.y);
      // jbmd = i*(B-D), scaled by sgn where used
      float jx = -(Bv.y - Dv.y) * sgn, jy = (Bv.x - Dv.x) * sgn;
      float2 u1 = make_float2(amc.x + jx, amc.y + jy);
      float2 u2 = make_float2(apc.x - bpd.x, apc.y - bpd.y);
      float2 u3 = make_float2(amc.x - jx, amc.y - jy);
      const int o = k + 4 * j;
      dst[o] = make_float2(apc.x + bpd.x, apc.y + bpd.y);
      dst[o + m] = make_float2(c1 * u1.x - s1 * u1.y, c1 * u1.y + s1 * u1.x);
      dst[o + 2 * m] = make_float2(c2 * u2.x - s2 * u2.y, c2 * u2.y + s2 * u2.x);
      dst[o + 3 * m] = make_float2(c3 * u3.x - s3 * u3.y, c3 * u3.y + s3 * u3.x);
    }
    __syncthreads();
    float2* t = src; src = dst; dst = t;
  }
  // final radix-2 stage (m = 1024): twiddle-free
#pragma unroll 1
  for (int i = tid; i < 1024; i += 256) {
    float2 A = src[i], Bv = src[i + 1024];
    dst[i] = make_float2(A.x + Bv.x, A.y + Bv.y);
    dst[i + 1024] = make_float2(A.x - Bv.x, A.y - Bv.y);
  }
  __syncthreads();
  return dst;
}

// ---------------------------------------------------------------------------
// corrT[b,c,:] = irfft(rfft(qT)*conj(rfft(kT))) along T, layout [B,C,T].
// 2 channels/block packed as one complex signal; Hermitian unpack pointwise.
// Fused epilogue: per-channel softmax stats M, 1/S -> Mv, Iv (row is in LDS).
// ---------------------------------------------------------------------------
__global__ __launch_bounds__(256)
void corr_fft_kernel(const float* qT, const float* kT, float* corrT,
                     float* __restrict__ Mv, float* __restrict__ Iv) {
  __shared__ float2 bA[2048];
  __shared__ float2 bB[2048];
  __shared__ float2 bC[2048];
  __shared__ float2 tw[512];
  __shared__ float2 red[4];
  const int tid = threadIdx.x;
  const int wave = tid >> 6, lane = tid & 63;
  const int b = blockIdx.y;
  const int c0 = blockIdx.x * 2;
  const float* q0 = qT + ((size_t)b * C_DIM + c0) * T_DIM;
  const float* k0p = kT + ((size_t)b * C_DIM + c0) * T_DIM;

  // twiddle table
#pragma unroll 1
  for (int j = tid; j < 512; j += 256) {
    float sA, cA;
    __sincosf((float)j * (6.283185307179586f / 2048.0f), &sA, &cA);
    tw[j] = make_float2(cA, sA);
  }

  // load packed zq = q_c0 + i*q_{c0+1}
#pragma unroll 1
  for (int t = tid; t < T_DIM; t += 256)
    bA[t] = make_float2(q0[t], q0[t + T_DIM]);
  __syncthreads();
  float2* FQ = fft2048_r4(bA, bB, tw, tid, -1.0f);   // -> bA

#pragma unroll 1
  for (int t = tid; t < T_DIM; t += 256)
    bB[t] = make_float2(k0p[t], k0p[t + T_DIM]);
  __syncthreads();
  float2* FK = fft2048_r4(bB, bC, tw, tid, -1.0f);   // -> bB

  // pointwise: unpack A/B spectra, cross-spectra G,H, repack W = G + i*H -> bC
#pragma unroll 1
  for (int f = tid; f < T_DIM; f += 256) {
    const int f2 = (T_DIM - f) & (T_DIM - 1);
    float2 Zq = FQ[f], Zq2 = FQ[f2];
    float2 Zk = FK[f], Zk2 = FK[f2];
    float2 Aq = make_float2(0.5f * (Zq.x + Zq2.x), 0.5f * (Zq.y - Zq2.y));
    float2 Dq = make_float2(Zq.x - Zq2.x, Zq.y + Zq2.y);
    float2 Bq = make_float2(0.5f * Dq.y, -0.5f * Dq.x);
    float2 Ak = make_float2(0.5f * (Zk.x + Zk2.x), 0.5f * (Zk.y - Zk2.y));
    float2 Dk = make_float2(Zk.x - Zk2.x, Zk.y + Zk2.y);
    float2 Bk = make_float2(0.5f * Dk.y, -0.5f * Dk.x);
    float2 G = make_float2(Aq.x * Ak.x + Aq.y * Ak.y, Aq.y * Ak.x - Aq.x * Ak.y);
    float2 H = make_float2(Bq.x * Bk.x + Bq.y * Bk.y, Bq.y * Bk.x - Bq.x * Bk.y);
    bC[f] = make_float2(G.x - H.y, G.y + H.x);
  }
  __syncthreads();
  float2* OUT = fft2048_r4(bC, bB, tw, tid, +1.0f);  // -> bC

  float* o0 = corrT + ((size_t)b * C_DIM + c0) * T_DIM;
  const float sc = 1.0f / 2048.0f;
  float mx0 = -INFINITY, mx1 = -INFINITY;
#pragma unroll 1
  for (int t = tid; t < T_DIM; t += 256) {
    float2 o = OUT[t];
    float v0 = o.x * sc, v1 = o.y * sc;
    o0[t] = v0;
    o0[t + T_DIM] = v1;
    mx0 = fmaxf(mx0, v0);
    mx1 = fmaxf(mx1, v1);
  }
  // block max reduce (both channels)
#pragma unroll
  for (int off = 32; off > 0; off >>= 1) {
    mx0 = fmaxf(mx0, __shfl_down(mx0, off));
    mx1 = fmaxf(mx1, __shfl_down(mx1, off));
  }
  if (lane == 0) red[wave] = make_float2(mx0, mx1);
  __syncthreads();
  const float M0 = fmaxf(fmaxf(red[0].x, red[1].x), fmaxf(red[2].x, red[3].x));
  const float M1 = fmaxf(fmaxf(red[0].y, red[1].y), fmaxf(red[2].y, red[3].y));
  __syncthreads();
  float s0 = 0.f, s1 = 0.f;
#pragma unroll 1
  for (int t = tid; t < T_DIM; t += 256) {
    float2 o = OUT[t];
    s0 += __expf(o.x * sc - M0);
    s1 += __expf(o.y * sc - M1);
  }
#pragma unroll
  for (int off = 32; off > 0; off >>= 1) {
    s0 += __shfl_down(s0, off);
    s1 += __shfl_down(s1, off);
  }
  if (lane == 0) red[wave] = make_float2(s0, s1);
  __syncthreads();
  if (tid == 0) {
    float S0 = red[0].x + red[1].x + red[2].x + red[3].x;
    float S1 = red[0].y + red[1].y + red[2].y + red[3].y;
    Mv[(size_t)b * C_DIM + c0] = M0;
    Mv[(size_t)b * C_DIM + c0 + 1] = M1;
    Iv[(size_t)b * C_DIM + c0] = 1.0f / S0;
    Iv[(size_t)b * C_DIM + c0 + 1] = 1.0f / S1;
  }
}

// ---------------------------------------------------------------------------
// Fused: attn[b,t,c] = exp(corrT[b,c,t]-M[b,c]) * I[b,c] * sv[b,t],
// with 32x32 LDS tiled transpose [B,C,T] -> [B,T,C].
// ---------------------------------------------------------------------------
__global__ __launch_bounds__(256)
void attn_transpose_kernel(const float* __restrict__ corrT, const float* __restrict__ Mv,
                           const float* __restrict__ Iv, const float* __restrict__ sv,
                           float* __restrict__ attn) {
  __shared__ float tile[32][33];
  const int tid = threadIdx.x;
  const int tx = tid & 31, ty = tid >> 5;   // ty 0..7
  const int t0 = blockIdx.x * 32, c0 = blockIdx.y * 32, b = blockIdx.z;
  const float svv = sv[(size_t)b * T_DIM + t0 + tx];
#pragma unroll
  for (int i = 0; i < 4; i++) {
    const int c = c0 + ty + i * 8;
    const float M = Mv[(size_t)b * C_DIM + c];
    const float I = Iv[(size_t)b * C_DIM + c];
    float v = corrT[((size_t)b * C_DIM + c) * T_DIM + t0 + tx];
    tile[ty + i * 8][tx] = __expf(v - M) * I * svv;
  }
  __syncthreads();
#pragma unroll
  for (int i = 0; i < 4; i++) {
    const int t = t0 + ty + i * 8;
    attn[((size_t)b * T_DIM + t) * C_DIM + c0 + tx] = tile[tx][ty + i * 8];
  }
}

// ---------------------------------------------------------------------------
// out = LayerNorm(A + Bv) * g + be; optional bf16 copy of out.
// ---------------------------------------------------------------------------
__global__ __launch_bounds__(256)
void add_ln_kernel(const float* __restrict__ A, const float* __restrict__ Bv,
                   const float* __restrict__ g, const float* __restrict__ be,
                   float* __restrict__ outf, unsigned short* outb) {
  const int r = blockIdx.x;
  const int tid = threadIdx.x;
  const size_t base = (size_t)r * C_DIM + (tid << 2);
  float4 a = *(const float4*)(A + base);
  float4 b = *(const float4*)(Bv + base);
  float x0 = a.x + b.x, x1 = a.y + b.y, x2 = a.z + b.z, x3 = a.w + b.w;
  float s = x0 + x1 + x2 + x3;
  float s2 = x0 * x0 + x1 * x1 + x2 * x2 + x3 * x3;
#pragma unroll
  for (int off = 32; off > 0; off >>= 1) {
    s += __shfl_down(s, off);
    s2 += __shfl_down(s2, off);
  }
  __shared__ float ps[4], ps2[4];
  if ((tid & 63) == 0) { ps[tid >> 6] = s; ps2[tid >> 6] = s2; }
  __syncthreads();
  float S = ps[0] + ps[1] + ps[2] + ps[3];
  float S2 = ps2[0] + ps2[1] + ps2[2] + ps2[3];
  const float mu = S * (1.0f / C_DIM);
  const float var = S2 * (1.0f / C_DIM) - mu * mu;
  const float rs = rsqrtf(var + LN_EPS);
  float4 gv = *(const float4*)(g + (tid << 2));
  float4 bev = *(const float4*)(be + (tid << 2));
  float o0 = (x0 - mu) * rs * gv.x + bev.x;
  float o1 = (x1 - mu) * rs * gv.y + bev.y;
  float o2 = (x2 - mu) * rs * gv.z + bev.z;
  float o3 = (x3 - mu) * rs * gv.w + bev.w;
  *(float4*)(outf + base) = make_float4(o0, o1, o2, o3);
  if (outb) *(ushort4*)(outb + base) = make_ushort4(f2bf(o0), f2bf(o1), f2bf(o2), f2bf(o3));
}

// ---------------------------------------------------------------------------
extern "C" void kernel_launch(void* const* d_in, const int* in_sizes, int n_in,
                              void* d_out, int out_size, void* d_ws, size_t ws_size,
                              hipStream_t stream) {
  const float* x   = (const float*)d_in[0];
  const float* Wq  = (const float*)d_in[1];
  const float* bq  = (const float*)d_in[2];
  const float* Wk  = (const float*)d_in[3];
  const float* bk  = (const float*)d_in[4];
  const float* Wv  = (const float*)d_in[5];
  const float* bv  = (const float*)d_in[6];
  const float* g1  = (const float*)d_in[7];
  const float* be1 = (const float*)d_in[8];
  const float* W1  = (const float*)d_in[9];
  const float* bf1 = (const float*)d_in[10];
  const float* W2  = (const float*)d_in[11];
  const float* bf2 = (const float*)d_in[12];
  const float* g2  = (const float*)d_in[13];
  const float* be2 = (const float*)d_in[14];
  float* out = (float*)d_out;

  // Workspace: qbuf(64M) kbuf(64M) xhi(32M) xlo(32M) wA(2M) wB(2M) + small
  float* ws = (float*)d_ws;
  float* qbuf = ws;                                   // qT -> corrT -> x1 fp32
  float* kbuf = ws + FSZ;                             // kT -> attn[B,T,C] -> h2 fp32
  unsigned short* xhi = (unsigned short*)(ws + 2 * FSZ);  // x_hi f16, later x1 bf16
  unsigned short* xlo = xhi + FSZ;                        // x_lo f16, later h1 bf16
  unsigned short* wA = xlo + FSZ;                     // 1M half/bf16
  unsigned short* wB = wA + (size_t)C_DIM * C_DIM;    // 1M half/bf16
  float* sv = (float*)(wB + (size_t)C_DIM * C_DIM);   // [B*T]
  float* wvsum = sv + BT_DIM;                         // [C]
  float* bvsum = wvsum + C_DIM;                       // [1]
  float* Mv = bvsum + 1;                              // [B*C]
  float* Iv = Mv + (size_t)B_DIM * C_DIM;             // [B*C]

  const dim3 blk(256);
  const dim3 ggrid(C_DIM / 128, BT_DIM / 128);        // (8, 128)
  const dim3 tgrid(C_DIM / 32, C_DIM / 32);           // (32, 32)

  // x -> (hi, lo) f16
  cvt_split_f16_kernel<<<dim3(FSZ / 1024), blk, 0, stream>>>(x, xhi, xlo);

  // sv[b,t] = x[b,t,:] . rowsum(Wv) + sum(bv)   (v GEMM eliminated)
  wv_rowsum_kernel<<<dim3(C_DIM + 1), blk, 0, stream>>>(Wv, bv, wvsum, bvsum);
  sv_dot_kernel<<<dim3(BT_DIM), blk, 0, stream>>>(x, wvsum, bvsum, sv);

  // qT = (x @ Wq + bq)^T per batch  (f16 2-pass split, [B,C,T] output)
  wtrans_f16_kernel<<<tgrid, blk, 0, stream>>>(Wq, wA, C_DIM, C_DIM);
  gemm_splitT_f16_kernel<<<ggrid, blk, 0, stream>>>((const _Float16*)xhi, (const _Float16*)xlo,
                                                    (const _Float16*)wA, bq, qbuf, C_DIM, C_DIM);
  // kT likewise
  wtrans_f16_kernel<<<tgrid, blk, 0, stream>>>(Wk, wA, C_DIM, C_DIM);
  gemm_splitT_f16_kernel<<<ggrid, blk, 0, stream>>>((const _Float16*)xhi, (const _Float16*)xlo,
                                                    (const _Float16*)wA, bk, kbuf, C_DIM, C_DIM);

  // corrT (in place over qbuf) + fused softmax stats
  corr_fft_kernel<<<dim3(C_DIM / 2, B_DIM), blk, 0, stream>>>(qbuf, kbuf, qbuf, Mv, Iv);

  // fused exp*scale*sv + transpose -> attn [B,T,C] (into kbuf)
  attn_transpose_kernel<<<dim3(T_DIM / 32, C_DIM / 32, B_DIM), blk, 0, stream>>>(
      qbuf, Mv, Iv, sv, kbuf);

  // x1 = LN(x + attn): fp32 -> qbuf, bf16 -> xhi region
  add_ln_kernel<<<dim3(BT_DIM), blk, 0, stream>>>(x, kbuf, g1, be1, qbuf, xhi);

  // FFN weights (plain bf16, transposed)
  wtrans_kernel<<<tgrid, blk, 0, stream>>>(W1, wA, C_DIM, C_DIM);
  wtrans_kernel<<<tgrid, blk, 0, stream>>>(W2, wB, C_DIM, C_DIM);

  // h1 = relu(x1 @ W1 + bf1) -> bf16 only (xlo region)
  gemm_bf16_kernel<<<ggrid, blk, 0, stream>>>((const __bf16*)xhi, (const __bf16*)wA,
                                              bf1, nullptr, xlo, C_DIM, C_DIM, 1);
  // h2 = h1 @ W2 + bf2 -> fp32 (kbuf)
  gemm_bf16_kernel<<<ggrid, blk, 0, stream>>>((const __bf16*)xlo, (const __bf16*)wB,
                                              bf2, kbuf, nullptr, C_DIM, C_DIM, 0);

  // out = LN(x1 + h2)
  add_ln_kernel<<<dim3(BT_DIM), blk, 0, stream>>>(qbuf, kbuf, g2, be2, out, nullptr);
}

// Round 5
// 580.823 us; speedup vs baseline: 4.8260x; 1.1844x over previous
//
#include <hip/hip_runtime.h>
#include <math.h>

// Problem constants (fixed-shape: B=8, T=2048, C=1024, fp32 in/out)
#define B_DIM 8
#define T_DIM 2048
#define C_DIM 1024
#define BT_DIM (B_DIM * T_DIM)                 // 16384 rows
#define FSZ ((size_t)BT_DIM * C_DIM)           // 16,777,216 elements per [B,T,C]
#define LN_EPS 1e-5f

typedef __bf16 bf16x8 __attribute__((ext_vector_type(8)));
typedef _Float16 f16x8 __attribute__((ext_vector_type(8)));
typedef float f32x4 __attribute__((ext_vector_type(4)));

__device__ __forceinline__ unsigned short f2bf(float f) {
  __bf16 h = (__bf16)f;
  return __builtin_bit_cast(unsigned short, h);
}
__device__ __forceinline__ unsigned short f2h(float f) {
  _Float16 h = (_Float16)f;
  return __builtin_bit_cast(unsigned short, h);
}

// async global->LDS, 16 B per lane. LDS dest must be wave-uniform base + lane*16.
__device__ __forceinline__ void gld16(const void* g, void* l) {
  __builtin_amdgcn_global_load_lds(
      (const __attribute__((address_space(1))) unsigned int*)g,
      (__attribute__((address_space(3))) unsigned int*)l, 16, 0, 0);
}

// LDS bank swizzle for float2 arrays: bank-pair = idx mod 16. XOR low 4 bits
// with a hash of higher bits -> butterfly strides {512,128,32,8,2} land on
// distinct bank pairs; contiguous access stays conflict-free (in-block perm).
__device__ __forceinline__ int swz(int a) {
  return a ^ (((a >> 4) ^ (a >> 8)) & 15);
}

// digit-reversal map of the radix-4^5 x 2 DIF: frequency f -> storage pos.
__device__ __forceinline__ int enc11(int f) {
  return ((f & 3) << 9) | (((f >> 2) & 3) << 7) | (((f >> 4) & 3) << 5) |
         (((f >> 6) & 3) << 3) | (((f >> 8) & 3) << 1) | ((f >> 10) & 1);
}

// ---------------------------------------------------------------------------
// x fp32 -> (hi, lo) f16 split: hi = f16(x), lo = f16(x - hi)  (~21 mant bits)
// ---------------------------------------------------------------------------
__global__ __launch_bounds__(256)
void cvt_split_f16_kernel(const float* __restrict__ x, unsigned short* __restrict__ hi,
                          unsigned short* __restrict__ lo) {
  size_t idx = ((size_t)blockIdx.x * 256 + threadIdx.x) * 4;
  float4 v = *(const float4*)(x + idx);
  float f[4] = {v.x, v.y, v.z, v.w};
  unsigned short hv[4], lv[4];
#pragma unroll
  for (int i = 0; i < 4; i++) {
    _Float16 hb = (_Float16)f[i];
    hv[i] = __builtin_bit_cast(unsigned short, hb);
    lv[i] = f2h(f[i] - (float)hb);
  }
  *(ushort4*)(hi + idx) = make_ushort4(hv[0], hv[1], hv[2], hv[3]);
  *(ushort4*)(lo + idx) = make_ushort4(lv[0], lv[1], lv[2], lv[3]);
}

// ---------------------------------------------------------------------------
// W [K,N] fp32 -> Wt [N,K] f16. 32x32 LDS tiles.
// ---------------------------------------------------------------------------
__global__ __launch_bounds__(256)
void wtrans_f16_kernel(const float* __restrict__ W, unsigned short* __restrict__ Wt,
                       int K, int N) {
  __shared__ float tile[32][33];
  const int tid = threadIdx.x;
  const int tx = tid & 31, ty = tid >> 5;
  const int n0 = blockIdx.x * 32, k0 = blockIdx.y * 32;
#pragma unroll
  for (int i = 0; i < 4; i++) {
    int row = ty + i * 8;
    tile[row][tx] = W[(size_t)(k0 + row) * N + n0 + tx];
  }
  __syncthreads();
#pragma unroll
  for (int i = 0; i < 4; i++) {
    int row = ty + i * 8;
    Wt[(size_t)(n0 + row) * K + k0 + tx] = f2h(tile[tx][row]);
  }
}

// ---------------------------------------------------------------------------
// W [K,N] fp32 -> Wt [N,K] bf16. For the FFN weights.
// ---------------------------------------------------------------------------
__global__ __launch_bounds__(256)
void wtrans_kernel(const float* __restrict__ W, unsigned short* __restrict__ Wt,
                   int K, int N) {
  __shared__ float tile[32][33];
  const int tid = threadIdx.x;
  const int tx = tid & 31, ty = tid >> 5;
  const int n0 = blockIdx.x * 32, k0 = blockIdx.y * 32;
#pragma unroll
  for (int i = 0; i < 4; i++) {
    int row = ty + i * 8;
    tile[row][tx] = W[(size_t)(k0 + row) * N + n0 + tx];
  }
  __syncthreads();
#pragma unroll
  for (int i = 0; i < 4; i++) {
    int row = ty + i * 8;
    Wt[(size_t)(n0 + row) * K + k0 + tx] = f2bf(tile[tx][row]);
  }
}

// ---------------------------------------------------------------------------
// wvsum[k] = sum_n Wv[k,n]  (blocks 0..K-1); block K reduces bv -> bvsum.
// ---------------------------------------------------------------------------
__global__ __launch_bounds__(256)
void wv_rowsum_kernel(const float* __restrict__ Wv, const float* __restrict__ bv,
                      float* __restrict__ wvsum, float* __restrict__ bvsum) {
  const int r = blockIdx.x;
  const int tid = threadIdx.x;
  const float* src = (r < C_DIM) ? (Wv + (size_t)r * C_DIM) : bv;
  float4 t4 = *(const float4*)(src + (tid << 2));
  float s = t4.x + t4.y + t4.z + t4.w;
#pragma unroll
  for (int off = 32; off > 0; off >>= 1) s += __shfl_down(s, off);
  __shared__ float ps[4];
  if ((tid & 63) == 0) ps[tid >> 6] = s;
  __syncthreads();
  if (tid == 0) {
    float v = ps[0] + ps[1] + ps[2] + ps[3];
    if (r < C_DIM) wvsum[r] = v; else bvsum[0] = v;
  }
}

// ---------------------------------------------------------------------------
// sv[r] = dot(x[r,:], wvsum) + bvsum
// ---------------------------------------------------------------------------
__global__ __launch_bounds__(256)
void sv_dot_kernel(const float* __restrict__ x, const float* __restrict__ wvsum,
                   const float* __restrict__ bvsum, float* __restrict__ sv) {
  const int r = blockIdx.x;
  const int tid = threadIdx.x;
  float4 a = *(const float4*)(x + (size_t)r * C_DIM + (tid << 2));
  float4 w = *(const float4*)(wvsum + (tid << 2));
  float s = a.x * w.x + a.y * w.y + a.z * w.z + a.w * w.w;
#pragma unroll
  for (int off = 32; off > 0; off >>= 1) s += __shfl_down(s, off);
  __shared__ float ps[4];
  if ((tid & 63) == 0) ps[tid >> 6] = s;
  __syncthreads();
  if (tid == 0) sv[r] = ps[0] + ps[1] + ps[2] + ps[3] + bvsum[0];
}

// ---------------------------------------------------------------------------
// bf16 MFMA GEMM (m97 structure): Y[M,N] = A[M,K] @ Bt[N,K]^T + bias. FFN.
// ---------------------------------------------------------------------------
__global__ __launch_bounds__(256, 2)
void gemm_bf16_kernel(const __bf16* __restrict__ A, const __bf16* __restrict__ Bt,
                      const float* __restrict__ bias, float* Yf, unsigned short* Yb,
                      int K, int N, int do_relu) {
  __shared__ __align__(16) __bf16 As[128 * 32];
  __shared__ __align__(16) __bf16 Bs[128 * 32];
  const int tid = threadIdx.x;
  const int wave = tid >> 6, lane = tid & 63;
  const int wr = wave >> 1, wc = wave & 1;
  const int r15 = lane & 15, kq = lane >> 4;
  const int m0 = blockIdx.y * 128, n0 = blockIdx.x * 128;

  f32x4 acc[4][4] = {};

  for (int k0 = 0; k0 < K; k0 += 32) {
#pragma unroll
    for (int r = 0; r < 2; ++r) {
      int idx = r * 256 + tid;
      int row = idx >> 2;
      int ko = (idx & 3) ^ ((row >> 1) & 3);
      gld16(A + (size_t)(m0 + row) * K + k0 + ko * 8, &As[idx * 8]);
      gld16(Bt + (size_t)(n0 + row) * K + k0 + ko * 8, &Bs[idx * 8]);
    }
    __syncthreads();
    bf16x8 afr[4], bfr[4];
#pragma unroll
    for (int i = 0; i < 4; i++) {
      int ar = wr * 64 + i * 16 + r15;
      afr[i] = *(const bf16x8*)&As[(ar * 4 + (kq ^ ((ar >> 1) & 3))) * 8];
      int br = wc * 64 + i * 16 + r15;
      bfr[i] = *(const bf16x8*)&Bs[(br * 4 + (kq ^ ((br >> 1) & 3))) * 8];
    }
#pragma unroll
    for (int mi = 0; mi < 4; mi++)
#pragma unroll
      for (int ni = 0; ni < 4; ni++)
        acc[mi][ni] = __builtin_amdgcn_mfma_f32_16x16x32_bf16(afr[mi], bfr[ni], acc[mi][ni], 0, 0, 0);
    __syncthreads();
  }

  float bv[4];
#pragma unroll
  for (int ni = 0; ni < 4; ni++) bv[ni] = bias[n0 + wc * 64 + ni * 16 + r15];

#pragma unroll
  for (int mi = 0; mi < 4; mi++)
#pragma unroll
    for (int ni = 0; ni < 4; ni++) {
      const int n = n0 + wc * 64 + ni * 16 + r15;
#pragma unroll
      for (int r = 0; r < 4; r++) {
        const int m = m0 + wr * 64 + mi * 16 + kq * 4 + r;
        float v = acc[mi][ni][r] + bv[ni];
        if (do_relu) v = fmaxf(v, 0.f);
        if (Yf) Yf[(size_t)m * N + n] = v;
        if (Yb) Yb[(size_t)m * N + n] = f2bf(v);
      }
    }
}

// ---------------------------------------------------------------------------
// FUSED q+k split-f16 GEMM with TRANSPOSED outputs: Yq/Yk [B,C,T] fp32.
// A (hi+lo f16) staged once; dual B operands + dual accumulators.
// Yx[b][n][t] = sum_k (Ahi+Alo)[m,k]*Bx[n,k] + bias_x[n],  m = b*T + t.
// ---------------------------------------------------------------------------
__global__ __launch_bounds__(256, 2)
void gemm_qkT_f16_kernel(const _Float16* __restrict__ Ahi, const _Float16* __restrict__ Alo,
                         const _Float16* __restrict__ Bq, const _Float16* __restrict__ Bk,
                         const float* __restrict__ biasq, const float* __restrict__ biask,
                         float* __restrict__ Yq, float* __restrict__ Yk, int K, int N) {
  __shared__ __align__(16) _Float16 Ash[128 * 32];
  __shared__ __align__(16) _Float16 Asl[128 * 32];
  __shared__ __align__(16) _Float16 Bsq[128 * 32];
  __shared__ __align__(16) _Float16 Bsk[128 * 32];
  const int tid = threadIdx.x;
  const int wave = tid >> 6, lane = tid & 63;
  const int wr = wave >> 1, wc = wave & 1;
  const int r15 = lane & 15, kq = lane >> 4;
  const int m0 = blockIdx.y * 128, n0 = blockIdx.x * 128;

  f32x4 accq[4][4] = {};
  f32x4 acck[4][4] = {};

  for (int k0 = 0; k0 < K; k0 += 32) {
#pragma unroll
    for (int r = 0; r < 2; ++r) {
      int idx = r * 256 + tid;
      int row = idx >> 2;
      int ko = (idx & 3) ^ ((row >> 1) & 3);
      size_t ga = (size_t)(m0 + row) * K + k0 + ko * 8;
      size_t gb = (size_t)(n0 + row) * K + k0 + ko * 8;
      gld16(Ahi + ga, &Ash[idx * 8]);
      gld16(Alo + ga, &Asl[idx * 8]);
      gld16(Bq + gb, &Bsq[idx * 8]);
      gld16(Bk + gb, &Bsk[idx * 8]);
    }
    __syncthreads();
    f16x8 ah[4], al[4], bqf[4], bkf[4];
#pragma unroll
    for (int i = 0; i < 4; i++) {
      int ar = wr * 64 + i * 16 + r15;
      int as = (ar * 4 + (kq ^ ((ar >> 1) & 3))) * 8;
      ah[i] = *(const f16x8*)&Ash[as];
      al[i] = *(const f16x8*)&Asl[as];
      int br = wc * 64 + i * 16 + r15;
      int bs = (br * 4 + (kq ^ ((br >> 1) & 3))) * 8;
      bqf[i] = *(const f16x8*)&Bsq[bs];
      bkf[i] = *(const f16x8*)&Bsk[bs];
    }
#pragma unroll
    for (int mi = 0; mi < 4; mi++)
#pragma unroll
      for (int ni = 0; ni < 4; ni++) {
        f32x4 cq = accq[mi][ni];
        cq = __builtin_amdgcn_mfma_f32_16x16x32_f16(ah[mi], bqf[ni], cq, 0, 0, 0);
        cq = __builtin_amdgcn_mfma_f32_16x16x32_f16(al[mi], bqf[ni], cq, 0, 0, 0);
        accq[mi][ni] = cq;
        f32x4 ck = acck[mi][ni];
        ck = __builtin_amdgcn_mfma_f32_16x16x32_f16(ah[mi], bkf[ni], ck, 0, 0, 0);
        ck = __builtin_amdgcn_mfma_f32_16x16x32_f16(al[mi], bkf[ni], ck, 0, 0, 0);
        acck[mi][ni] = ck;
      }
    __syncthreads();
  }

  float bvq[4], bvk[4];
#pragma unroll
  for (int ni = 0; ni < 4; ni++) {
    bvq[ni] = biasq[n0 + wc * 64 + ni * 16 + r15];
    bvk[ni] = biask[n0 + wc * 64 + ni * 16 + r15];
  }

#pragma unroll
  for (int mi = 0; mi < 4; mi++) {
    const int mbase = m0 + wr * 64 + mi * 16 + kq * 4;  // 4 consecutive m
    const int bb = mbase >> 11;                          // batch (T=2048)
    const int t = mbase & (T_DIM - 1);
#pragma unroll
    for (int ni = 0; ni < 4; ni++) {
      const int n = n0 + wc * 64 + ni * 16 + r15;
      const size_t o = ((size_t)bb * C_DIM + n) * T_DIM + t;
      *(float4*)(Yq + o) = make_float4(accq[mi][ni][0] + bvq[ni], accq[mi][ni][1] + bvq[ni],
                                       accq[mi][ni][2] + bvq[ni], accq[mi][ni][3] + bvq[ni]);
      *(float4*)(Yk + o) = make_float4(acck[mi][ni][0] + bvk[ni], acck[mi][ni][1] + bvk[ni],
                                       acck[mi][ni][2] + bvk[ni], acck[mi][ni][3] + bvk[ni]);
    }
  }
}

// ---------------------------------------------------------------------------
// In-place 2048-pt FFT, radix-4 DIF (5 stages) + radix-2: natural input ->
// digit-reversed output (enc11 map). sgn=-1 forward. All LDS indices swizzled.
// ---------------------------------------------------------------------------
__device__ void fft_dif(float2* X, const float2* tw, int tid, float sgn) {
#pragma unroll
  for (int s = 0; s < 5; s++) {
    const int m = 512 >> (2 * s);
    const int jstep = 512 / m;  // 4^s
#pragma unroll
    for (int ii = 0; ii < 2; ii++) {
      const int i = tid + ii * 256;
      const int q = i & (m - 1);
      const int a0 = ((i - q) << 2) + q;
      float2 x0 = X[swz(a0)];
      float2 x1 = X[swz(a0 + m)];
      float2 x2 = X[swz(a0 + 2 * m)];
      float2 x3 = X[swz(a0 + 3 * m)];
      float2 t0 = make_float2(x0.x + x2.x, x0.y + x2.y);
      float2 t2 = make_float2(x0.x - x2.x, x0.y - x2.y);
      float2 t1 = make_float2(x1.x + x3.x, x1.y + x3.y);
      float2 t3 = make_float2(x1.x - x3.x, x1.y - x3.y);
      const float jx = -sgn * t3.y, jy = sgn * t3.x;   // sgn*i*t3
      float2 y0 = make_float2(t0.x + t1.x, t0.y + t1.y);
      float2 y1 = make_float2(t2.x + jx, t2.y + jy);
      float2 y2 = make_float2(t0.x - t1.x, t0.y - t1.y);
      float2 y3 = make_float2(t2.x - jx, t2.y - jy);
      const int j1 = q * jstep;
      float2 tv = tw[swz(j1)];
      const float c1 = tv.x, s1 = tv.y * sgn;
      const float c2 = c1 * c1 - s1 * s1, s2 = 2.f * c1 * s1;
      const float c3 = c2 * c1 - s2 * s1, s3 = c2 * s1 + s2 * c1;
      X[swz(a0)] = y0;
      X[swz(a0 + m)] = make_float2(c1 * y1.x - s1 * y1.y, c1 * y1.y + s1 * y1.x);
      X[swz(a0 + 2 * m)] = make_float2(c2 * y2.x - s2 * y2.y, c2 * y2.y + s2 * y2.x);
      X[swz(a0 + 3 * m)] = make_float2(c3 * y3.x - s3 * y3.y, c3 * y3.y + s3 * y3.x);
    }
    __syncthreads();
  }
  // final radix-2 on adjacent pairs, twiddle-free
#pragma unroll
  for (int ii = 0; ii < 4; ii++) {
    const int a = (tid + ii * 256) << 1;
    float2 u = X[swz(a)], v = X[swz(a + 1)];
    X[swz(a)] = make_float2(u.x + v.x, u.y + v.y);
    X[swz(a + 1)] = make_float2(u.x - v.x, u.y - v.y);
  }
  __syncthreads();
}

// In-place inverse (adjoint of fft_dif, unnormalized): digit-reversed input ->
// natural output. Radix-2 first, then 5 DIT radix-4 stages (twiddle-before).
__device__ void fft_dit_inv(float2* X, const float2* tw, int tid) {
#pragma unroll
  for (int ii = 0; ii < 4; ii++) {
    const int a = (tid + ii * 256) << 1;
    float2 u = X[swz(a)], v = X[swz(a + 1)];
    X[swz(a)] = make_float2(u.x + v.x, u.y + v.y);
    X[swz(a + 1)] = make_float2(u.x - v.x, u.y - v.y);
  }
  __syncthreads();
#pragma unroll
  for (int s = 4; s >= 0; s--) {
    const int m = 512 >> (2 * s);
    const int jstep = 512 / m;
#pragma unroll
    for (int ii = 0; ii < 2; ii++) {
      const int i = tid + ii * 256;
      const int q = i & (m - 1);
      const int a0 = ((i - q) << 2) + q;
      float2 v0 = X[swz(a0)];
      float2 v1 = X[swz(a0 + m)];
      float2 v2 = X[swz(a0 + 2 * m)];
      float2 v3 = X[swz(a0 + 3 * m)];
      const int j1 = q * jstep;
      float2 tv = tw[swz(j1)];
      const float c1 = tv.x, s1 = tv.y;  // e^{+i theta}
      const float c2 = c1 * c1 - s1 * s1, s2 = 2.f * c1 * s1;
      const float c3 = c2 * c1 - s2 * s1, s3 = c2 * s1 + s2 * c1;
      float2 w1 = make_float2(c1 * v1.x - s1 * v1.y, c1 * v1.y + s1 * v1.x);
      float2 w2 = make_float2(c2 * v2.x - s2 * v2.y, c2 * v2.y + s2 * v2.x);
      float2 w3 = make_float2(c3 * v3.x - s3 * v3.y, c3 * v3.y + s3 * v3.x);
      float2 t0 = make_float2(v0.x + w2.x, v0.y + w2.y);
      float2 t2 = make_float2(v0.x - w2.x, v0.y - w2.y);
      float2 t1 = make_float2(w1.x + w3.x, w1.y + w3.y);
      float2 t3 = make_float2(w1.x - w3.x, w1.y - w3.y);
      const float jx = -t3.y, jy = t3.x;  // +i*t3
      X[swz(a0)] = make_float2(t0.x + t1.x, t0.y + t1.y);
      X[swz(a0 + m)] = make_float2(t2.x + jx, t2.y + jy);
      X[swz(a0 + 2 * m)] = make_float2(t0.x - t1.x, t0.y - t1.y);
      X[swz(a0 + 3 * m)] = make_float2(t2.x - jx, t2.y - jy);
    }
    __syncthreads();
  }
}

// ---------------------------------------------------------------------------
// corrT[b,c,:] = irfft(rfft(qT)*conj(rfft(kT))) along T, layout [B,C,T].
// 2 channels/block packed; cross-spectrum computed in digit-reversed domain
// (Hermitian conj trick: W(N-f) = conj(G) + i*conj(H)). In-place FFTs ->
// only 2 LDS buffers (36.9 KB -> 4 blocks/CU). Fused softmax stats epilogue.
// ---------------------------------------------------------------------------
__global__ __launch_bounds__(256)
void corr_fft_kernel(const float* qT, const float* kT, float* corrT,
                     float* __restrict__ Mv, float* __restrict__ Iv) {
  __shared__ float2 bA[2048];
  __shared__ float2 bB[2048];
  __shared__ float2 tw[512];
  __shared__ float2 red[4];
  const int tid = threadIdx.x;
  const int wave = tid >> 6, lane = tid & 63;
  const int b = blockIdx.y;
  const int c0 = blockIdx.x * 2;
  const float* q0 = qT + ((size_t)b * C_DIM + c0) * T_DIM;
  const float* k0p = kT + ((size_t)b * C_DIM + c0) * T_DIM;

  // twiddle table tw[j] = (cos,sin)(2*pi*j/2048), stored swizzled
#pragma unroll
  for (int jj = 0; jj < 2; jj++) {
    int j = tid + jj * 256;
    float sA, cA;
    __sincosf((float)j * (6.283185307179586f / 2048.0f), &sA, &cA);
    tw[swz(j)] = make_float2(cA, sA);
  }

  // load packed zq = q_c0 + i*q_{c0+1}; zk likewise
#pragma unroll
  for (int jj = 0; jj < 8; jj++) {
    int t = tid + jj * 256;
    bA[swz(t)] = make_float2(q0[t], q0[t + T_DIM]);
    bB[swz(t)] = make_float2(k0p[t], k0p[t + T_DIM]);
  }
  __syncthreads();

  fft_dif(bA, tw, tid, -1.0f);   // FQ, digit-reversed, in place
  fft_dif(bB, tw, tid, -1.0f);   // FK, digit-reversed, in place

  // pointwise over Hermitian pairs (f, 2048-f): unpack both channels,
  // cross-spectra G,H, W = G+iH; partner via conjugation. In place over bA.
#pragma unroll 1
  for (int f = tid; f <= 1024; f += 256) {
    const int g = (2048 - f) & 2047;
    const int p = swz(enc11(f));
    const int p2 = swz(enc11(g));
    float2 Zq = bA[p], Zq2 = bA[p2];
    float2 Zk = bB[p], Zk2 = bB[p2];
    float2 Aq = make_float2(0.5f * (Zq.x + Zq2.x), 0.5f * (Zq.y - Zq2.y));
    float2 Dq = make_float2(Zq.x - Zq2.x, Zq.y + Zq2.y);
    float2 Bq = make_float2(0.5f * Dq.y, -0.5f * Dq.x);
    float2 Ak = make_float2(0.5f * (Zk.x + Zk2.x), 0.5f * (Zk.y - Zk2.y));
    float2 Dk = make_float2(Zk.x - Zk2.x, Zk.y + Zk2.y);
    float2 Bk = make_float2(0.5f * Dk.y, -0.5f * Dk.x);
    float2 G = make_float2(Aq.x * Ak.x + Aq.y * Ak.y, Aq.y * Ak.x - Aq.x * Ak.y);
    float2 H = make_float2(Bq.x * Bk.x + Bq.y * Bk.y, Bq.y * Bk.x - Bq.x * Bk.y);
    bA[p] = make_float2(G.x - H.y, G.y + H.x);
    if (p2 != p) bA[p2] = make_float2(G.x + H.y, -G.y + H.x);
  }
  __syncthreads();

  fft_dit_inv(bA, tw, tid);      // natural order, unnormalized

  // epilogue: scale, store both channels, fused softmax stats (max, sum-exp)
  float* o0 = corrT + ((size_t)b * C_DIM + c0) * T_DIM;
  const float sc = 1.0f / 2048.0f;
  float mx0 = -INFINITY, mx1 = -INFINITY;
#pragma unroll
  for (int jj = 0; jj < 8; jj++) {
    int t = tid + jj * 256;
    float2 o = bA[swz(t)];
    float v0 = o.x * sc, v1 = o.y * sc;
    o0[t] = v0;
    o0[t + T_DIM] = v1;
    mx0 = fmaxf(mx0, v0);
    mx1 = fmaxf(mx1, v1);
  }
#pragma unroll
  for (int off = 32; off > 0; off >>= 1) {
    mx0 = fmaxf(mx0, __shfl_down(mx0, off));
    mx1 = fmaxf(mx1, __shfl_down(mx1, off));
  }
  if (lane == 0) red[wave] = make_float2(mx0, mx1);
  __syncthreads();
  const float M0 = fmaxf(fmaxf(red[0].x, red[1].x), fmaxf(red[2].x, red[3].x));
  const float M1 = fmaxf(fmaxf(red[0].y, red[1].y), fmaxf(red[2].y, red[3].y));
  __syncthreads();
  float s0 = 0.f, s1 = 0.f;
#pragma unroll
  for (int jj = 0; jj < 8; jj++) {
    int t = tid + jj * 256;
    float2 o = bA[swz(t)];
    s0 += __expf(o.x * sc - M0);
    s1 += __expf(o.y * sc - M1);
  }
#pragma unroll
  for (int off = 32; off > 0; off >>= 1) {
    s0 += __shfl_down(s0, off);
    s1 += __shfl_down(s1, off);
  }
  if (lane == 0) red[wave] = make_float2(s0, s1);
  __syncthreads();
  if (tid == 0) {
    float S0 = red[0].x + red[1].x + red[2].x + red[3].x;
    float S1 = red[0].y + red[1].y + red[2].y + red[3].y;
    Mv[(size_t)b * C_DIM + c0] = M0;
    Mv[(size_t)b * C_DIM + c0 + 1] = M1;
    Iv[(size_t)b * C_DIM + c0] = 1.0f / S0;
    Iv[(size_t)b * C_DIM + c0 + 1] = 1.0f / S1;
  }
}

// ---------------------------------------------------------------------------
// Fused: attn[b,t,c] = exp(corrT[b,c,t]-M[b,c]) * I[b,c] * sv[b,t],
// with 32x32 LDS tiled transpose [B,C,T] -> [B,T,C].
// ---------------------------------------------------------------------------
__global__ __launch_bounds__(256)
void attn_transpose_kernel(const float* __restrict__ corrT, const float* __restrict__ Mv,
                           const float* __restrict__ Iv, const float* __restrict__ sv,
                           float* __restrict__ attn) {
  __shared__ float tile[32][33];
  const int tid = threadIdx.x;
  const int tx = tid & 31, ty = tid >> 5;   // ty 0..7
  const int t0 = blockIdx.x * 32, c0 = blockIdx.y * 32, b = blockIdx.z;
  const float svv = sv[(size_t)b * T_DIM + t0 + tx];
#pragma unroll
  for (int i = 0; i < 4; i++) {
    const int c = c0 + ty + i * 8;
    const float M = Mv[(size_t)b * C_DIM + c];
    const float I = Iv[(size_t)b * C_DIM + c];
    float v = corrT[((size_t)b * C_DIM + c) * T_DIM + t0 + tx];
    tile[ty + i * 8][tx] = __expf(v - M) * I * svv;
  }
  __syncthreads();
#pragma unroll
  for (int i = 0; i < 4; i++) {
    const int t = t0 + ty + i * 8;
    attn[((size_t)b * T_DIM + t) * C_DIM + c0 + tx] = tile[tx][ty + i * 8];
  }
}

// ---------------------------------------------------------------------------
// out = LayerNorm(A + Bv) * g + be; optional bf16 copy of out.
// ---------------------------------------------------------------------------
__global__ __launch_bounds__(256)
void add_ln_kernel(const float* __restrict__ A, const float* __restrict__ Bv,
                   const float* __restrict__ g, const float* __restrict__ be,
                   float* __restrict__ outf, unsigned short* outb) {
  const int r = blockIdx.x;
  const int tid = threadIdx.x;
  const size_t base = (size_t)r * C_DIM + (tid << 2);
  float4 a = *(const float4*)(A + base);
  float4 b = *(const float4*)(Bv + base);
  float x0 = a.x + b.x, x1 = a.y + b.y, x2 = a.z + b.z, x3 = a.w + b.w;
  float s = x0 + x1 + x2 + x3;
  float s2 = x0 * x0 + x1 * x1 + x2 * x2 + x3 * x3;
#pragma unroll
  for (int off = 32; off > 0; off >>= 1) {
    s += __shfl_down(s, off);
    s2 += __shfl_down(s2, off);
  }
  __shared__ float ps[4], ps2[4];
  if ((tid & 63) == 0) { ps[tid >> 6] = s; ps2[tid >> 6] = s2; }
  __syncthreads();
  float S = ps[0] + ps[1] + ps[2] + ps[3];
  float S2 = ps2[0] + ps2[1] + ps2[2] + ps2[3];
  const float mu = S * (1.0f / C_DIM);
  const float var = S2 * (1.0f / C_DIM) - mu * mu;
  const float rs = rsqrtf(var + LN_EPS);
  float4 gv = *(const float4*)(g + (tid << 2));
  float4 bev = *(const float4*)(be + (tid << 2));
  float o0 = (x0 - mu) * rs * gv.x + bev.x;
  float o1 = (x1 - mu) * rs * gv.y + bev.y;
  float o2 = (x2 - mu) * rs * gv.z + bev.z;
  float o3 = (x3 - mu) * rs * gv.w + bev.w;
  *(float4*)(outf + base) = make_float4(o0, o1, o2, o3);
  if (outb) *(ushort4*)(outb + base) = make_ushort4(f2bf(o0), f2bf(o1), f2bf(o2), f2bf(o3));
}

// ---------------------------------------------------------------------------
extern "C" void kernel_launch(void* const* d_in, const int* in_sizes, int n_in,
                              void* d_out, int out_size, void* d_ws, size_t ws_size,
                              hipStream_t stream) {
  const float* x   = (const float*)d_in[0];
  const float* Wq  = (const float*)d_in[1];
  const float* bq  = (const float*)d_in[2];
  const float* Wk  = (const float*)d_in[3];
  const float* bk  = (const float*)d_in[4];
  const float* Wv  = (const float*)d_in[5];
  const float* bv  = (const float*)d_in[6];
  const float* g1  = (const float*)d_in[7];
  const float* be1 = (const float*)d_in[8];
  const float* W1  = (const float*)d_in[9];
  const float* bf1 = (const float*)d_in[10];
  const float* W2  = (const float*)d_in[11];
  const float* bf2 = (const float*)d_in[12];
  const float* g2  = (const float*)d_in[13];
  const float* be2 = (const float*)d_in[14];
  float* out = (float*)d_out;

  // Workspace: qbuf(64M) kbuf(64M) xhi(32M) xlo(32M) wA(2M) wB(2M) + small
  float* ws = (float*)d_ws;
  float* qbuf = ws;                                   // qT -> corrT -> x1 fp32
  float* kbuf = ws + FSZ;                             // kT -> attn[B,T,C] -> h2 fp32
  unsigned short* xhi = (unsigned short*)(ws + 2 * FSZ);  // x_hi f16, later x1 bf16
  unsigned short* xlo = xhi + FSZ;                        // x_lo f16, later h1 bf16
  unsigned short* wA = xlo + FSZ;                     // 1M half/bf16
  unsigned short* wB = wA + (size_t)C_DIM * C_DIM;    // 1M half/bf16
  float* sv = (float*)(wB + (size_t)C_DIM * C_DIM);   // [B*T]
  float* wvsum = sv + BT_DIM;                         // [C]
  float* bvsum = wvsum + C_DIM;                       // [1]
  float* Mv = bvsum + 1;                              // [B*C]
  float* Iv = Mv + (size_t)B_DIM * C_DIM;             // [B*C]

  const dim3 blk(256);
  const dim3 ggrid(C_DIM / 128, BT_DIM / 128);        // (8, 128)
  const dim3 tgrid(C_DIM / 32, C_DIM / 32);           // (32, 32)

  // x -> (hi, lo) f16
  cvt_split_f16_kernel<<<dim3(FSZ / 1024), blk, 0, stream>>>(x, xhi, xlo);

  // sv[b,t] = x[b,t,:] . rowsum(Wv) + sum(bv)   (v GEMM eliminated)
  wv_rowsum_kernel<<<dim3(C_DIM + 1), blk, 0, stream>>>(Wv, bv, wvsum, bvsum);
  sv_dot_kernel<<<dim3(BT_DIM), blk, 0, stream>>>(x, wvsum, bvsum, sv);

  // qT,kT = (x @ Wq/Wk + b)^T per batch — fused, A staged once
  wtrans_f16_kernel<<<tgrid, blk, 0, stream>>>(Wq, wA, C_DIM, C_DIM);
  wtrans_f16_kernel<<<tgrid, blk, 0, stream>>>(Wk, wB, C_DIM, C_DIM);
  gemm_qkT_f16_kernel<<<ggrid, blk, 0, stream>>>((const _Float16*)xhi, (const _Float16*)xlo,
                                                 (const _Float16*)wA, (const _Float16*)wB,
                                                 bq, bk, qbuf, kbuf, C_DIM, C_DIM);

  // corrT (in place over qbuf) + fused softmax stats
  corr_fft_kernel<<<dim3(C_DIM / 2, B_DIM), blk, 0, stream>>>(qbuf, kbuf, qbuf, Mv, Iv);

  // fused exp*scale*sv + transpose -> attn [B,T,C] (into kbuf)
  attn_transpose_kernel<<<dim3(T_DIM / 32, C_DIM / 32, B_DIM), blk, 0, stream>>>(
      qbuf, Mv, Iv, sv, kbuf);

  // x1 = LN(x + attn): fp32 -> qbuf, bf16 -> xhi region
  add_ln_kernel<<<dim3(BT_DIM), blk, 0, stream>>>(x, kbuf, g1, be1, qbuf, xhi);

  // FFN weights (plain bf16, transposed)
  wtrans_kernel<<<tgrid, blk, 0, stream>>>(W1, wA, C_DIM, C_DIM);
  wtrans_kernel<<<tgrid, blk, 0, stream>>>(W2, wB, C_DIM, C_DIM);

  // h1 = relu(x1 @ W1 + bf1) -> bf16 only (xlo region)
  gemm_bf16_kernel<<<ggrid, blk, 0, stream>>>((const __bf16*)xhi, (const __bf16*)wA,
                                              bf1, nullptr, xlo, C_DIM, C_DIM, 1);
  // h2 = h1 @ W2 + bf2 -> fp32 (kbuf)
  gemm_bf16_kernel<<<ggrid, blk, 0, stream>>>((const __bf16*)xlo, (const __bf16*)wB,
                                              bf2, kbuf, nullptr, C_DIM, C_DIM, 0);

  // out = LN(x1 + h2)
  add_ln_kernel<<<dim3(BT_DIM), blk, 0, stream>>>(qbuf, kbuf, g2, be2, out, nullptr);
}